// Round 1
// baseline (240.838 us; speedup 1.0000x reference)
//
#include <hip/hip_runtime.h>

// Problem: B=2, C=256, F*H*W=N=4096, heads=4, dim_head=64, inner=256
#define BATCH 2
#define CCH   256
#define NSEQ  4096
#define NH    4
#define DH    64
#define INNER 256

typedef __attribute__((ext_vector_type(8))) __bf16 bf16x8;
typedef __attribute__((ext_vector_type(4))) float f32x4;
typedef __attribute__((ext_vector_type(8))) unsigned short u16x8;

static __device__ __forceinline__ unsigned short f2bf(float f) {
  union { float f; unsigned u; } v; v.f = f;
  unsigned r = v.u + 0x7fffu + ((v.u >> 16) & 1u);   // RNE; inputs finite
  return (unsigned short)(r >> 16);
}
static __device__ __forceinline__ float bf2f(unsigned short u) {
  union { unsigned u; float f; } v; v.u = ((unsigned)u) << 16;
  return v.f;
}
static __device__ __forceinline__ bf16x8 ldb(const unsigned short* p) {
  return *(const bf16x8*)p;
}
static __device__ __forceinline__ f32x4 mm(bf16x8 a, bf16x8 b, f32x4 c) {
  return __builtin_amdgcn_mfma_f32_16x16x32_bf16(a, b, c, 0, 0, 0);
}

// ---------------- Kernel 1: channel LayerNorm -> xn [b][n][c] bf16 ----------
__global__ __launch_bounds__(256) void k_ln(const float* __restrict__ x,
                                            const float* __restrict__ gamma,
                                            unsigned short* __restrict__ xn) {
  int blk = blockIdx.x;            // 256 blocks: b = blk>>7, 32 n-positions each
  int b  = blk >> 7;
  int n0 = (blk & 127) * 32;
  int t  = threadIdx.x;
  int nl = t & 31;                 // position within tile
  int cg = t >> 5;                 // channel group 0..7 (32 channels each)
  int n  = n0 + nl;
  const float* xp = x + ((size_t)(b * CCH + cg * 32)) * NSEQ + n;
  float vals[32];
  float s = 0.f, s2 = 0.f;
#pragma unroll
  for (int j = 0; j < 32; j++) {
    float v = xp[(size_t)j * NSEQ];
    vals[j] = v; s += v; s2 += v * v;
  }
  __shared__ float rs[8][32], rs2[8][32];
  rs[cg][nl] = s; rs2[cg][nl] = s2;
  __syncthreads();
  float S = 0.f, S2 = 0.f;
#pragma unroll
  for (int g = 0; g < 8; g++) { S += rs[g][nl]; S2 += rs2[g][nl]; }
  float mean = S * (1.f / 256.f);
  float var  = S2 * (1.f / 256.f) - mean * mean;
  float rstd = rsqrtf(var + 1e-5f);
  unsigned short* dst = xn + ((size_t)b * NSEQ + n) * CCH + cg * 32;
#pragma unroll
  for (int j0 = 0; j0 < 32; j0 += 8) {
    u16x8 pk;
#pragma unroll
    for (int j = 0; j < 8; j++)
      pk[j] = f2bf((vals[j0 + j] - mean) * rstd * gamma[cg * 32 + j0 + j]);
    *(u16x8*)(dst + j0) = pk;
  }
}

// ---------------- Kernel 2: QKV GEMM  qkv[b][o][n] = wq[o][c] * xn[b][n][c] -
__global__ __launch_bounds__(256) void k_qkv(const float* __restrict__ wq,
                                             const unsigned short* __restrict__ xn,
                                             unsigned short* __restrict__ qkv) {
  int n0 = blockIdx.x * 64;
  int o0 = blockIdx.y * 64;
  int b  = blockIdx.z;
  __shared__ unsigned short Al[64 * 40];   // [o][c] pad->stride40 (2-way max)
  __shared__ unsigned short Bl[64 * 40];   // [n][c]
  int t = threadIdx.x;
  int lane = t & 63, w = t >> 6;
  int c = lane & 15, quad = lane >> 4;
  int wm = w >> 1, wn = w & 1;
  f32x4 acc[2][2] = {};
  int r = t >> 2, seg = (t & 3) * 8;
  const float* apg = wq + (size_t)(o0 + r) * CCH + seg;
  const unsigned short* bpg = xn + ((size_t)b * NSEQ + n0 + r) * CCH + seg;
  for (int kt = 0; kt < 8; kt++) {
    if (kt) __syncthreads();
    u16x8 av;
#pragma unroll
    for (int j = 0; j < 8; j++) av[j] = f2bf(apg[kt * 32 + j]);
    *(u16x8*)&Al[r * 40 + seg] = av;
    *(u16x8*)&Bl[r * 40 + seg] = *(const u16x8*)(bpg + kt * 32);
    __syncthreads();
    bf16x8 a0 = ldb(&Al[(wm * 32      + c) * 40 + quad * 8]);
    bf16x8 a1 = ldb(&Al[(wm * 32 + 16 + c) * 40 + quad * 8]);
    bf16x8 b0 = ldb(&Bl[(wn * 32      + c) * 40 + quad * 8]);
    bf16x8 b1 = ldb(&Bl[(wn * 32 + 16 + c) * 40 + quad * 8]);
    acc[0][0] = mm(a0, b0, acc[0][0]);
    acc[0][1] = mm(a0, b1, acc[0][1]);
    acc[1][0] = mm(a1, b0, acc[1][0]);
    acc[1][1] = mm(a1, b1, acc[1][1]);
  }
#pragma unroll
  for (int i = 0; i < 2; i++)
#pragma unroll
    for (int j = 0; j < 2; j++)
#pragma unroll
      for (int rr = 0; rr < 4; rr++) {
        int o = o0 + wm * 32 + i * 16 + quad * 4 + rr;
        int n = n0 + wn * 32 + j * 16 + c;
        qkv[((size_t)b * 768 + o) * NSEQ + n] = f2bf(acc[i][j][rr]);
      }
}

// ------- Kernel 3: l2norm over d + transpose q,k -> [b][h][n][d] bf16 -------
__global__ __launch_bounds__(256) void k_nrm(const unsigned short* __restrict__ qkv,
                                             unsigned short* __restrict__ qt,
                                             unsigned short* __restrict__ ktb) {
  int n0 = blockIdx.x * 64;
  int sh = blockIdx.y;                 // sel*4 + h, sel: 0=q 1=k
  int b  = blockIdx.z;
  int sel = sh >> 2, h = sh & 3;
  int t = threadIdx.x;
  int col = t & 63, rg = t >> 6;       // rg: 16 d-rows each
  const unsigned short* src =
      qkv + ((size_t)b * 768 + sel * 256 + h * 64 + rg * 16) * NSEQ + n0 + col;
  float v[16];
  float sq = 0.f;
#pragma unroll
  for (int d = 0; d < 16; d++) {
    float f = bf2f(src[(size_t)d * NSEQ]);
    v[d] = f; sq += f * f;
  }
  __shared__ float red[4][64];
  red[rg][col] = sq;
  __syncthreads();
  float tot = red[0][col] + red[1][col] + red[2][col] + red[3][col];
  float rn = rsqrtf(tot + 1e-12f);
  unsigned short* dst = (sel ? ktb : qt) +
      (((size_t)b * NH + h) * NSEQ + n0 + col) * DH + rg * 16;
#pragma unroll
  for (int j0 = 0; j0 < 16; j0 += 8) {
    u16x8 pk;
#pragma unroll
    for (int j = 0; j < 8; j++) pk[j] = f2bf(v[j0 + j] * rn);
    *(u16x8*)(dst + j0) = pk;
  }
}

// ---------------- Kernel 4: flash attention -> ao [b][n][inner] fp32 --------
__global__ __launch_bounds__(256) void k_attn(const unsigned short* __restrict__ qt,
                                              const unsigned short* __restrict__ ktb,
                                              const unsigned short* __restrict__ qkv,
                                              float* __restrict__ ao) {
  int i0 = blockIdx.x * 64;
  int h  = blockIdx.y;
  int b  = blockIdx.z;
  __shared__ unsigned short Ql[64 * 72];   // [i][d]
  __shared__ unsigned short Kl[64 * 72];   // [j][d]
  __shared__ unsigned short Vl[64 * 72];   // [d][j]  (v stored [d][n] globally)
  __shared__ unsigned short Pl[64 * 72];   // [i][j]
  int t = threadIdx.x;
  int lane = t & 63, w = t >> 6;
  int c = lane & 15, quad = lane >> 4;
  int r = t >> 2, seg = (t & 3) * 16;

  const unsigned short* qbase = qt  + ((size_t)(b * NH + h) * NSEQ) * DH;
  const unsigned short* kbase = ktb + ((size_t)(b * NH + h) * NSEQ) * DH;
  const unsigned short* vbase = qkv + ((size_t)b * 768 + 512 + h * 64) * NSEQ;

  {
    const unsigned short* p = qbase + (size_t)(i0 + r) * DH + seg;
    *(u16x8*)&Ql[r * 72 + seg]     = *(const u16x8*)p;
    *(u16x8*)&Ql[r * 72 + seg + 8] = *(const u16x8*)(p + 8);
  }
  __syncthreads();
  bf16x8 qf0 = ldb(&Ql[(w * 16 + c) * 72 + quad * 8]);
  bf16x8 qf1 = ldb(&Ql[(w * 16 + c) * 72 + 32 + quad * 8]);

  f32x4 acc[4] = {};
  float m_run[4], l_run[4];
#pragma unroll
  for (int i = 0; i < 4; i++) { m_run[i] = -1e30f; l_run[i] = 0.f; }

  for (int j0 = 0; j0 < NSEQ; j0 += 64) {
    {
      const unsigned short* p = kbase + (size_t)(j0 + r) * DH + seg;
      *(u16x8*)&Kl[r * 72 + seg]     = *(const u16x8*)p;
      *(u16x8*)&Kl[r * 72 + seg + 8] = *(const u16x8*)(p + 8);
      const unsigned short* pv = vbase + (size_t)r * NSEQ + j0 + seg;
      *(u16x8*)&Vl[r * 72 + seg]     = *(const u16x8*)pv;
      *(u16x8*)&Vl[r * 72 + seg + 8] = *(const u16x8*)(pv + 8);
    }
    __syncthreads();

    f32x4 s[4];
#pragma unroll
    for (int jt = 0; jt < 4; jt++) {
      f32x4 z = {};
      z = mm(qf0, ldb(&Kl[(jt * 16 + c) * 72 + quad * 8]), z);
      z = mm(qf1, ldb(&Kl[(jt * 16 + c) * 72 + 32 + quad * 8]), z);
      s[jt] = z;
    }
#pragma unroll
    for (int jt = 0; jt < 4; jt++)
#pragma unroll
      for (int rr = 0; rr < 4; rr++) s[jt][rr] *= 8.f;   // SCALE

    float mt[4];
#pragma unroll
    for (int rr = 0; rr < 4; rr++) {
      float m0 = fmaxf(fmaxf(s[0][rr], s[1][rr]), fmaxf(s[2][rr], s[3][rr]));
#pragma unroll
      for (int off = 1; off < 16; off <<= 1) m0 = fmaxf(m0, __shfl_xor(m0, off));
      mt[rr] = m0;
    }
    float alpha[4], psum[4];
#pragma unroll
    for (int rr = 0; rr < 4; rr++) {
      float mn = fmaxf(m_run[rr], mt[rr]);
      alpha[rr] = __expf(m_run[rr] - mn);
      m_run[rr] = mn;
      psum[rr] = 0.f;
    }
#pragma unroll
    for (int jt = 0; jt < 4; jt++)
#pragma unroll
      for (int rr = 0; rr < 4; rr++) {
        float p = __expf(s[jt][rr] - m_run[rr]);
        s[jt][rr] = p;
        psum[rr] += p;
      }
#pragma unroll
    for (int rr = 0; rr < 4; rr++) {
#pragma unroll
      for (int off = 1; off < 16; off <<= 1) psum[rr] += __shfl_xor(psum[rr], off);
      l_run[rr] = l_run[rr] * alpha[rr] + psum[rr];
    }
#pragma unroll
    for (int dt = 0; dt < 4; dt++)
#pragma unroll
      for (int rr = 0; rr < 4; rr++) acc[dt][rr] *= alpha[rr];

    // P (C-layout regs) -> LDS [i][j] for the A-operand of PV
#pragma unroll
    for (int jt = 0; jt < 4; jt++)
#pragma unroll
      for (int rr = 0; rr < 4; rr++)
        Pl[(w * 16 + quad * 4 + rr) * 72 + jt * 16 + c] = f2bf(s[jt][rr]);
    __syncthreads();

    bf16x8 pa0 = ldb(&Pl[(w * 16 + c) * 72 + quad * 8]);
    bf16x8 pa1 = ldb(&Pl[(w * 16 + c) * 72 + 32 + quad * 8]);
#pragma unroll
    for (int dt = 0; dt < 4; dt++) {
      acc[dt] = mm(pa0, ldb(&Vl[(dt * 16 + c) * 72 + quad * 8]), acc[dt]);
      acc[dt] = mm(pa1, ldb(&Vl[(dt * 16 + c) * 72 + 32 + quad * 8]), acc[dt]);
    }
    __syncthreads();
  }

#pragma unroll
  for (int rr = 0; rr < 4; rr++) {
    float inv = 1.f / l_run[rr];
    int i = i0 + w * 16 + quad * 4 + rr;
#pragma unroll
    for (int dt = 0; dt < 4; dt++)
      ao[((size_t)b * NSEQ + i) * INNER + h * 64 + dt * 16 + c] = acc[dt][rr] * inv;
  }
}

// ------- Kernel 5: out-proj + residual: out[b][o][n] = wo*ao + x ------------
__global__ __launch_bounds__(256) void k_out(const float* __restrict__ wo,
                                             const float* __restrict__ ao,
                                             const float* __restrict__ x,
                                             float* __restrict__ out) {
  int n0 = blockIdx.x * 64;
  int o0 = blockIdx.y * 64;
  int b  = blockIdx.z;
  __shared__ unsigned short Al[64 * 40];
  __shared__ unsigned short Bl[64 * 40];
  int t = threadIdx.x;
  int lane = t & 63, w = t >> 6;
  int c = lane & 15, quad = lane >> 4;
  int wm = w >> 1, wn = w & 1;
  f32x4 acc[2][2] = {};
  int r = t >> 2, seg = (t & 3) * 8;
  const float* apg = wo + (size_t)(o0 + r) * INNER + seg;
  const float* bpg = ao + ((size_t)b * NSEQ + n0 + r) * INNER + seg;
  for (int kt = 0; kt < 8; kt++) {
    if (kt) __syncthreads();
    u16x8 av, bv;
#pragma unroll
    for (int j = 0; j < 8; j++) {
      av[j] = f2bf(apg[kt * 32 + j]);
      bv[j] = f2bf(bpg[kt * 32 + j]);
    }
    *(u16x8*)&Al[r * 40 + seg] = av;
    *(u16x8*)&Bl[r * 40 + seg] = bv;
    __syncthreads();
    bf16x8 a0 = ldb(&Al[(wm * 32      + c) * 40 + quad * 8]);
    bf16x8 a1 = ldb(&Al[(wm * 32 + 16 + c) * 40 + quad * 8]);
    bf16x8 b0 = ldb(&Bl[(wn * 32      + c) * 40 + quad * 8]);
    bf16x8 b1 = ldb(&Bl[(wn * 32 + 16 + c) * 40 + quad * 8]);
    acc[0][0] = mm(a0, b0, acc[0][0]);
    acc[0][1] = mm(a0, b1, acc[0][1]);
    acc[1][0] = mm(a1, b0, acc[1][0]);
    acc[1][1] = mm(a1, b1, acc[1][1]);
  }
#pragma unroll
  for (int i = 0; i < 2; i++)
#pragma unroll
    for (int j = 0; j < 2; j++)
#pragma unroll
      for (int rr = 0; rr < 4; rr++) {
        int o = o0 + wm * 32 + i * 16 + quad * 4 + rr;
        int n = n0 + wn * 32 + j * 16 + c;
        size_t idx = ((size_t)b * CCH + o) * NSEQ + n;
        out[idx] = acc[i][j][rr] + x[idx];
      }
}

extern "C" void kernel_launch(void* const* d_in, const int* in_sizes, int n_in,
                              void* d_out, int out_size, void* d_ws, size_t ws_size,
                              hipStream_t stream) {
  const float* x     = (const float*)d_in[0];
  const float* gamma = (const float*)d_in[1];
  const float* wq    = (const float*)d_in[2];
  const float* wo    = (const float*)d_in[3];
  float* out = (float*)d_out;

  char* ws = (char*)d_ws;
  // ws layout (33 MB total):
  float*          ao  = (float*)ws;                                  // [0,8MB)   fp32 [B][N][256]
  unsigned short* xn  = (unsigned short*)(ws + (size_t)(8  << 20));  // [8,12MB)  bf16 [B][N][256]
  unsigned short* qkv = (unsigned short*)(ws + (size_t)(12 << 20));  // [12,24.6) bf16 [B][768][N]
  unsigned short* qt  = (unsigned short*)(ws + (size_t)(25 << 20));  // [25,29)   bf16 [B][H][N][D]
  unsigned short* ktb = (unsigned short*)(ws + (size_t)(29 << 20));  // [29,33)   bf16 [B][H][N][D]

  k_ln  <<<dim3(256),        256, 0, stream>>>(x, gamma, xn);
  k_qkv <<<dim3(64, 12, 2),  256, 0, stream>>>(wq, xn, qkv);
  k_nrm <<<dim3(64, 8, 2),   256, 0, stream>>>(qkv, qt, ktb);
  k_attn<<<dim3(64, 4, 2),   256, 0, stream>>>(qt, ktb, qkv, ao);
  k_out <<<dim3(64, 4, 2),   256, 0, stream>>>(wo, ao, x, out);
}

// Round 2
// 185.175 us; speedup vs baseline: 1.3006x; 1.3006x over previous
//
#include <hip/hip_runtime.h>

// Problem: B=2, C=256, F*H*W=N=4096, heads=4, dim_head=64, inner=256
#define BATCH 2
#define CCH   256
#define NSEQ  4096
#define NH    4
#define DH    64
#define INNER 256

typedef __attribute__((ext_vector_type(8))) __bf16 bf16x8;
typedef __attribute__((ext_vector_type(4))) float f32x4;
typedef __attribute__((ext_vector_type(8))) unsigned short u16x8;
typedef __attribute__((ext_vector_type(4))) unsigned short u16x4;

static __device__ __forceinline__ unsigned short f2bf(float f) {
  union { float f; unsigned u; } v; v.f = f;
  unsigned r = v.u + 0x7fffu + ((v.u >> 16) & 1u);   // RNE; inputs finite
  return (unsigned short)(r >> 16);
}
static __device__ __forceinline__ float bf2f(unsigned short u) {
  union { unsigned u; float f; } v; v.u = ((unsigned)u) << 16;
  return v.f;
}
static __device__ __forceinline__ bf16x8 ldb(const unsigned short* p) {
  return *(const bf16x8*)p;
}
static __device__ __forceinline__ f32x4 mm(bf16x8 a, bf16x8 b, f32x4 c) {
  return __builtin_amdgcn_mfma_f32_16x16x32_bf16(a, b, c, 0, 0, 0);
}

// ---------------- Kernel 0: fp32->bf16 weight pre-convert -------------------
__global__ __launch_bounds__(256) void k_cvt(const float* __restrict__ wq,
                                             const float* __restrict__ wo,
                                             unsigned short* __restrict__ wqb,
                                             unsigned short* __restrict__ wob) {
  int t = blockIdx.x * 256 + threadIdx.x;          // 65536 threads x 4 elems
  int e = t * 4;
  if (e < 768 * 256) {
    float4 v = *(const float4*)(wq + e);
    u16x4 pk = { f2bf(v.x), f2bf(v.y), f2bf(v.z), f2bf(v.w) };
    *(u16x4*)(wqb + e) = pk;
  } else {
    int e2 = e - 768 * 256;
    float4 v = *(const float4*)(wo + e2);
    u16x4 pk = { f2bf(v.x), f2bf(v.y), f2bf(v.z), f2bf(v.w) };
    *(u16x4*)(wob + e2) = pk;
  }
}

// ---------------- Kernel 1: channel LayerNorm -> xn [b][n][c] bf16 ----------
__global__ __launch_bounds__(256) void k_ln(const float* __restrict__ x,
                                            const float* __restrict__ gamma,
                                            unsigned short* __restrict__ xn) {
  int blk = blockIdx.x;            // 256 blocks: b = blk>>7, 32 n-positions each
  int b  = blk >> 7;
  int n0 = (blk & 127) * 32;
  int t  = threadIdx.x;
  int nl = t & 31;                 // position within tile
  int cg = t >> 5;                 // channel group 0..7 (32 channels each)
  int n  = n0 + nl;
  const float* xp = x + ((size_t)(b * CCH + cg * 32)) * NSEQ + n;
  float vals[32];
  float s = 0.f, s2 = 0.f;
#pragma unroll
  for (int j = 0; j < 32; j++) {
    float v = xp[(size_t)j * NSEQ];
    vals[j] = v; s += v; s2 += v * v;
  }
  __shared__ float rs[8][32], rs2[8][32];
  rs[cg][nl] = s; rs2[cg][nl] = s2;
  __syncthreads();
  float S = 0.f, S2 = 0.f;
#pragma unroll
  for (int g = 0; g < 8; g++) { S += rs[g][nl]; S2 += rs2[g][nl]; }
  float mean = S * (1.f / 256.f);
  float var  = S2 * (1.f / 256.f) - mean * mean;
  float rstd = rsqrtf(var + 1e-5f);
  unsigned short* dst = xn + ((size_t)b * NSEQ + n) * CCH + cg * 32;
#pragma unroll
  for (int j0 = 0; j0 < 32; j0 += 8) {
    u16x8 pk;
#pragma unroll
    for (int j = 0; j < 8; j++)
      pk[j] = f2bf((vals[j0 + j] - mean) * rstd * gamma[cg * 32 + j0 + j]);
    *(u16x8*)(dst + j0) = pk;
  }
}

// ---------------- Kernel 2: QKV GEMM  qkv[b][o][n] = wq[o][c] * xn[b][n][c] -
__global__ __launch_bounds__(256) void k_qkv(const unsigned short* __restrict__ wqb,
                                             const unsigned short* __restrict__ xn,
                                             unsigned short* __restrict__ qkv) {
  int n0 = blockIdx.x * 64;
  int o0 = blockIdx.y * 64;
  int b  = blockIdx.z;
  __shared__ unsigned short Al[64 * 40];   // [o][c] pad->stride40 (2-way max)
  __shared__ unsigned short Bl[64 * 40];   // [n][c]
  int t = threadIdx.x;
  int lane = t & 63, w = t >> 6;
  int c = lane & 15, quad = lane >> 4;
  int wm = w >> 1, wn = w & 1;
  f32x4 acc[2][2] = {};
  int r = t >> 2, seg = (t & 3) * 8;
  const unsigned short* apg = wqb + (size_t)(o0 + r) * CCH + seg;
  const unsigned short* bpg = xn + ((size_t)b * NSEQ + n0 + r) * CCH + seg;
  for (int kt = 0; kt < 8; kt++) {
    if (kt) __syncthreads();
    *(u16x8*)&Al[r * 40 + seg] = *(const u16x8*)(apg + kt * 32);
    *(u16x8*)&Bl[r * 40 + seg] = *(const u16x8*)(bpg + kt * 32);
    __syncthreads();
    bf16x8 a0 = ldb(&Al[(wm * 32      + c) * 40 + quad * 8]);
    bf16x8 a1 = ldb(&Al[(wm * 32 + 16 + c) * 40 + quad * 8]);
    bf16x8 b0 = ldb(&Bl[(wn * 32      + c) * 40 + quad * 8]);
    bf16x8 b1 = ldb(&Bl[(wn * 32 + 16 + c) * 40 + quad * 8]);
    acc[0][0] = mm(a0, b0, acc[0][0]);
    acc[0][1] = mm(a0, b1, acc[0][1]);
    acc[1][0] = mm(a1, b0, acc[1][0]);
    acc[1][1] = mm(a1, b1, acc[1][1]);
  }
#pragma unroll
  for (int i = 0; i < 2; i++)
#pragma unroll
    for (int j = 0; j < 2; j++)
#pragma unroll
      for (int rr = 0; rr < 4; rr++) {
        int o = o0 + wm * 32 + i * 16 + quad * 4 + rr;
        int n = n0 + wn * 32 + j * 16 + c;
        qkv[((size_t)b * 768 + o) * NSEQ + n] = f2bf(acc[i][j][rr]);
      }
}

// ------- Kernel 3: l2norm over d + transpose q,k -> [b][h][n][d] bf16 -------
// q additionally scaled by 8*log2(e) so softmax can use exp2 directly.
__global__ __launch_bounds__(256) void k_nrm(const unsigned short* __restrict__ qkv,
                                             unsigned short* __restrict__ qt,
                                             unsigned short* __restrict__ ktb) {
  int n0 = blockIdx.x * 64;
  int sh = blockIdx.y;                 // sel*4 + h, sel: 0=q 1=k
  int b  = blockIdx.z;
  int sel = sh >> 2, h = sh & 3;
  int t = threadIdx.x;
  int col = t & 63, rg = t >> 6;       // rg: 16 d-rows each
  const unsigned short* src =
      qkv + ((size_t)b * 768 + sel * 256 + h * 64 + rg * 16) * NSEQ + n0 + col;
  float v[16];
  float sq = 0.f;
#pragma unroll
  for (int d = 0; d < 16; d++) {
    float f = bf2f(src[(size_t)d * NSEQ]);
    v[d] = f; sq += f * f;
  }
  __shared__ float red[4][64];
  red[rg][col] = sq;
  __syncthreads();
  float tot = red[0][col] + red[1][col] + red[2][col] + red[3][col];
  float rn = rsqrtf(tot + 1e-12f);
  if (sel == 0) rn *= 11.541560327111707f;   // 8 * log2(e)
  unsigned short* dst = (sel ? ktb : qt) +
      (((size_t)b * NH + h) * NSEQ + n0 + col) * DH + rg * 16;
#pragma unroll
  for (int j0 = 0; j0 < 16; j0 += 8) {
    u16x8 pk;
#pragma unroll
    for (int j = 0; j < 8; j++) pk[j] = f2bf(v[j0 + j] * rn);
    *(u16x8*)(dst + j0) = pk;
  }
}

// ---------------- Kernel 4: flash attention (split-KV) ----------------------
// Computes S^T = K*Q^T so softmax row i == lane&15 (2-shuffle reductions) and
// P writes are contiguous b64. Split s covers kv range [s*kvlen, (s+1)*kvlen).
// S>1: store unnormalized O + (m,l) partials; S==1: write normalized ao.
__global__ __launch_bounds__(256, 4) void k_attn(
    const unsigned short* __restrict__ qt,
    const unsigned short* __restrict__ ktb,
    const unsigned short* __restrict__ qkv,
    float* __restrict__ ao,
    unsigned short* __restrict__ opart,
    float* __restrict__ mpart, float* __restrict__ lpart,
    int S, int kvlen) {
  int i0 = blockIdx.x * 64;
  int h  = blockIdx.y;
  int bz = blockIdx.z;
  int b  = bz / S, s = bz % S;
  __shared__ unsigned short Ql[64 * 72];   // [i][d]
  __shared__ unsigned short Kl[64 * 72];   // [j][d]
  __shared__ unsigned short Vl[64 * 72];   // [d][j]  (v stored [d][n] globally)
  __shared__ unsigned short Pl[64 * 72];   // [i][j]
  int t = threadIdx.x;
  int lane = t & 63, w = t >> 6;
  int c = lane & 15, quad = lane >> 4;
  int r = t >> 2, seg = (t & 3) * 16;

  const unsigned short* qbase = qt  + ((size_t)(b * NH + h) * NSEQ) * DH;
  const unsigned short* kbase = ktb + ((size_t)(b * NH + h) * NSEQ) * DH;
  const unsigned short* vbase = qkv + ((size_t)b * 768 + 512 + h * 64) * NSEQ;

  {
    const unsigned short* p = qbase + (size_t)(i0 + r) * DH + seg;
    *(u16x8*)&Ql[r * 72 + seg]     = *(const u16x8*)p;
    *(u16x8*)&Ql[r * 72 + seg + 8] = *(const u16x8*)(p + 8);
  }
  __syncthreads();
  bf16x8 qf0 = ldb(&Ql[(w * 16 + c) * 72 + quad * 8]);        // d 0..31
  bf16x8 qf1 = ldb(&Ql[(w * 16 + c) * 72 + 32 + quad * 8]);   // d 32..63

  f32x4 acc[4] = {};
  float m_run = -1e30f, l_run = 0.f;   // per-lane row i = i0 + w*16 + (lane&15)

  int j_beg = s * kvlen, j_end = j_beg + kvlen;
  for (int j0 = j_beg; j0 < j_end; j0 += 64) {
    {
      const unsigned short* p = kbase + (size_t)(j0 + r) * DH + seg;
      *(u16x8*)&Kl[r * 72 + seg]     = *(const u16x8*)p;
      *(u16x8*)&Kl[r * 72 + seg + 8] = *(const u16x8*)(p + 8);
      const unsigned short* pv = vbase + (size_t)r * NSEQ + j0 + seg;
      *(u16x8*)&Vl[r * 72 + seg]     = *(const u16x8*)pv;
      *(u16x8*)&Vl[r * 72 + seg + 8] = *(const u16x8*)(pv + 8);
    }
    __syncthreads();

    // S^T tiles: st[jt] holds rows j = jt*16+quad*4+rr, col i = lane&15
    f32x4 st[4];
#pragma unroll
    for (int jt = 0; jt < 4; jt++) {
      f32x4 z = {};
      z = mm(ldb(&Kl[(jt * 16 + c) * 72 + quad * 8]),      qf0, z);
      z = mm(ldb(&Kl[(jt * 16 + c) * 72 + 32 + quad * 8]), qf1, z);
      st[jt] = z;
    }

    // row-max over all 64 j for row i = lane&15
    float mx = st[0][0];
#pragma unroll
    for (int jt = 0; jt < 4; jt++)
#pragma unroll
      for (int rr = 0; rr < 4; rr++) mx = fmaxf(mx, st[jt][rr]);
    mx = fmaxf(mx, __shfl_xor(mx, 16));
    mx = fmaxf(mx, __shfl_xor(mx, 32));
    float mnew = fmaxf(m_run, mx);
    float alpha = exp2f(m_run - mnew);
    m_run = mnew;

    float ps = 0.f;
#pragma unroll
    for (int jt = 0; jt < 4; jt++)
#pragma unroll
      for (int rr = 0; rr < 4; rr++) {
        float p = exp2f(st[jt][rr] - mnew);
        st[jt][rr] = p;
        ps += p;
      }
    ps += __shfl_xor(ps, 16);
    ps += __shfl_xor(ps, 32);
    l_run = l_run * alpha + ps;

    // broadcast alpha of row quad*4+rr (held at lane quad*4+rr) for acc scale
    float a0 = __shfl(alpha, quad * 4 + 0);
    float a1 = __shfl(alpha, quad * 4 + 1);
    float a2 = __shfl(alpha, quad * 4 + 2);
    float a3 = __shfl(alpha, quad * 4 + 3);
#pragma unroll
    for (int dt = 0; dt < 4; dt++) {
      acc[dt][0] *= a0; acc[dt][1] *= a1; acc[dt][2] *= a2; acc[dt][3] *= a3;
    }

    // P[i][j]: per lane fixed i = w*16+c, j = jt*16+quad*4+rr -> b64 writes
#pragma unroll
    for (int jt = 0; jt < 4; jt++) {
      u16x4 pk = { f2bf(st[jt][0]), f2bf(st[jt][1]),
                   f2bf(st[jt][2]), f2bf(st[jt][3]) };
      *(u16x4*)&Pl[(w * 16 + c) * 72 + jt * 16 + quad * 4] = pk;
    }
    __syncthreads();

    bf16x8 pa0 = ldb(&Pl[(w * 16 + c) * 72 + quad * 8]);
    bf16x8 pa1 = ldb(&Pl[(w * 16 + c) * 72 + 32 + quad * 8]);
#pragma unroll
    for (int dt = 0; dt < 4; dt++) {
      acc[dt] = mm(pa0, ldb(&Vl[(dt * 16 + c) * 72 + quad * 8]), acc[dt]);
      acc[dt] = mm(pa1, ldb(&Vl[(dt * 16 + c) * 72 + 32 + quad * 8]), acc[dt]);
    }
    __syncthreads();
  }

  if (S > 1) {
    size_t rb = ((size_t)(b * NH + h) * S + s) * NSEQ;
    if (quad == 0) {
      int i = i0 + w * 16 + c;
      mpart[rb + i] = m_run;
      lpart[rb + i] = l_run;
    }
#pragma unroll
    for (int rr = 0; rr < 4; rr++) {
      int i = i0 + w * 16 + quad * 4 + rr;
#pragma unroll
      for (int dt = 0; dt < 4; dt++)
        opart[(rb + i) * 64 + dt * 16 + c] = f2bf(acc[dt][rr]);
    }
  } else {
    float linv = 1.f / l_run;
    float i0v = __shfl(linv, quad * 4 + 0);
    float i1v = __shfl(linv, quad * 4 + 1);
    float i2v = __shfl(linv, quad * 4 + 2);
    float i3v = __shfl(linv, quad * 4 + 3);
    float iv[4] = { i0v, i1v, i2v, i3v };
#pragma unroll
    for (int rr = 0; rr < 4; rr++) {
      int i = i0 + w * 16 + quad * 4 + rr;
#pragma unroll
      for (int dt = 0; dt < 4; dt++)
        ao[((size_t)b * NSEQ + i) * INNER + h * 64 + dt * 16 + c] =
            acc[dt][rr] * iv[rr];
    }
  }
}

// ---------------- Kernel 4b: merge split-KV partials -> ao ------------------
__global__ __launch_bounds__(256) void k_merge(
    const unsigned short* __restrict__ opart,
    const float* __restrict__ mpart, const float* __restrict__ lpart,
    float* __restrict__ ao, int S) {
  int t = blockIdx.x * 256 + threadIdx.x;     // 131072 threads
  int row = t >> 2;                            // (b*NH+h)*NSEQ + i
  int dseg = (t & 3) * 16;
  int b = row / (NH * NSEQ);
  int rem = row - b * (NH * NSEQ);
  int h = rem / NSEQ;
  int i = rem - h * NSEQ;

  float ms[4], ls[4];
  float mmax = -1e30f;
  for (int s = 0; s < S; s++) {
    size_t rb = ((size_t)(b * NH + h) * S + s) * NSEQ + i;
    ms[s] = mpart[rb]; ls[s] = lpart[rb];
    mmax = fmaxf(mmax, ms[s]);
  }
  float o[16];
#pragma unroll
  for (int j = 0; j < 16; j++) o[j] = 0.f;
  float l = 0.f;
  for (int s = 0; s < S; s++) {
    float wgt = exp2f(ms[s] - mmax);
    l += wgt * ls[s];
    size_t rb = (((size_t)(b * NH + h) * S + s) * NSEQ + i) * 64 + dseg;
    u16x8 v0 = *(const u16x8*)(opart + rb);
    u16x8 v1 = *(const u16x8*)(opart + rb + 8);
#pragma unroll
    for (int j = 0; j < 8; j++) {
      o[j]     += wgt * bf2f(v0[j]);
      o[8 + j] += wgt * bf2f(v1[j]);
    }
  }
  float inv = 1.f / l;
  float* dst = ao + ((size_t)b * NSEQ + i) * INNER + h * 64 + dseg;
#pragma unroll
  for (int j = 0; j < 16; j++) dst[j] = o[j] * inv;
}

// ------- Kernel 5: out-proj + residual: out[b][o][n] = wo*ao + x ------------
__global__ __launch_bounds__(256) void k_out(const unsigned short* __restrict__ wob,
                                             const float* __restrict__ ao,
                                             const float* __restrict__ x,
                                             float* __restrict__ out) {
  int n0 = blockIdx.x * 64;
  int o0 = blockIdx.y * 64;
  int b  = blockIdx.z;
  __shared__ unsigned short Al[64 * 40];
  __shared__ unsigned short Bl[64 * 40];
  int t = threadIdx.x;
  int lane = t & 63, w = t >> 6;
  int c = lane & 15, quad = lane >> 4;
  int wm = w >> 1, wn = w & 1;
  f32x4 acc[2][2] = {};
  int r = t >> 2, seg = (t & 3) * 8;
  const unsigned short* apg = wob + (size_t)(o0 + r) * INNER + seg;
  const float* bpg = ao + ((size_t)b * NSEQ + n0 + r) * INNER + seg;
  for (int kt = 0; kt < 8; kt++) {
    if (kt) __syncthreads();
    u16x8 bv;
#pragma unroll
    for (int j = 0; j < 8; j++) bv[j] = f2bf(bpg[kt * 32 + j]);
    *(u16x8*)&Al[r * 40 + seg] = *(const u16x8*)(apg + kt * 32);
    *(u16x8*)&Bl[r * 40 + seg] = bv;
    __syncthreads();
    bf16x8 a0 = ldb(&Al[(wm * 32      + c) * 40 + quad * 8]);
    bf16x8 a1 = ldb(&Al[(wm * 32 + 16 + c) * 40 + quad * 8]);
    bf16x8 b0 = ldb(&Bl[(wn * 32      + c) * 40 + quad * 8]);
    bf16x8 b1 = ldb(&Bl[(wn * 32 + 16 + c) * 40 + quad * 8]);
    acc[0][0] = mm(a0, b0, acc[0][0]);
    acc[0][1] = mm(a0, b1, acc[0][1]);
    acc[1][0] = mm(a1, b0, acc[1][0]);
    acc[1][1] = mm(a1, b1, acc[1][1]);
  }
#pragma unroll
  for (int i = 0; i < 2; i++)
#pragma unroll
    for (int j = 0; j < 2; j++)
#pragma unroll
      for (int rr = 0; rr < 4; rr++) {
        int o = o0 + wm * 32 + i * 16 + quad * 4 + rr;
        int n = n0 + wn * 32 + j * 16 + c;
        size_t idx = ((size_t)b * CCH + o) * NSEQ + n;
        out[idx] = acc[i][j][rr] + x[idx];
      }
}

extern "C" void kernel_launch(void* const* d_in, const int* in_sizes, int n_in,
                              void* d_out, int out_size, void* d_ws, size_t ws_size,
                              hipStream_t stream) {
  const float* x     = (const float*)d_in[0];
  const float* gamma = (const float*)d_in[1];
  const float* wq    = (const float*)d_in[2];
  const float* wo    = (const float*)d_in[3];
  float* out = (float*)d_out;

  const size_t MB = 1u << 20;
  char* ws = (char*)d_ws;
  // ws layout:
  float*          ao  = (float*)ws;                            // [0,8) MB fp32 [B][N][256]
  unsigned short* xn  = (unsigned short*)(ws + 8 * MB);        // [8,12) bf16 [B][N][256]
  unsigned short* qkv = (unsigned short*)(ws + 12 * MB);       // [12,24) bf16 [B][768][N] (exactly 12 MB)
  unsigned short* wqb = (unsigned short*)(ws + 24 * MB);       // 384 KB
  unsigned short* wob = (unsigned short*)(ws + 24 * MB + 512 * 1024); // 128 KB
  unsigned short* qt  = (unsigned short*)(ws + 25 * MB);       // [25,29) bf16 [B][H][N][D]
  unsigned short* ktb = (unsigned short*)(ws + 29 * MB);       // [29,33) bf16 [B][H][N][D]
  unsigned short* opart = (unsigned short*)(ws + 33 * MB);     // S*B*H*N*64 bf16
  // m/l partials after opart (S=4: 16.78 MB -> ml at 50 MB; S=2: 8.39 -> 42 MB)
  int S;
  if (ws_size >= 52 * MB) S = 4;
  else if (ws_size >= 44 * MB) S = 2;
  else S = 1;
  size_t opart_bytes = (size_t)S * BATCH * NH * NSEQ * DH * 2;
  float* mpart = (float*)(ws + 33 * MB + opart_bytes);
  float* lpart = mpart + (size_t)S * BATCH * NH * NSEQ;
  int kvlen = NSEQ / S;

  k_cvt <<<dim3(256),        256, 0, stream>>>(wq, wo, wqb, wob);
  k_ln  <<<dim3(256),        256, 0, stream>>>(x, gamma, xn);
  k_qkv <<<dim3(64, 12, 2),  256, 0, stream>>>(wqb, xn, qkv);
  k_nrm <<<dim3(64, 8, 2),   256, 0, stream>>>(qkv, qt, ktb);
  k_attn<<<dim3(64, 4, 2 * S), 256, 0, stream>>>(qt, ktb, qkv, ao, opart,
                                                 mpart, lpart, S, kvlen);
  if (S > 1)
    k_merge<<<dim3(512), 256, 0, stream>>>(opart, mpart, lpart, ao, S);
  k_out <<<dim3(64, 4, 2),   256, 0, stream>>>(wob, ao, x, out);
}

// Round 3
// 153.795 us; speedup vs baseline: 1.5660x; 1.2040x over previous
//
#include <hip/hip_runtime.h>

// Problem: B=2, C=256, F*H*W=N=4096, heads=4, dim_head=64, inner=256
#define BATCH 2
#define CCH   256
#define NSEQ  4096
#define NH    4
#define DH    64
#define INNER 256

typedef __attribute__((ext_vector_type(8))) __bf16 bf16x8;
typedef __attribute__((ext_vector_type(4))) float f32x4;
typedef __attribute__((ext_vector_type(8))) unsigned short u16x8;
typedef __attribute__((ext_vector_type(4))) unsigned short u16x4;

// round-half-up bf16 (inputs finite; bias vs RNE is <=0.5ulp, irrelevant here)
static __device__ __forceinline__ unsigned short f2bfr(float f) {
  union { float f; unsigned u; } v; v.f = f;
  return (unsigned short)((v.u + 0x8000u) >> 16);
}
// pack two floats -> bf16 pair (low = f0)
static __device__ __forceinline__ unsigned pack2(float f0, float f1) {
  union { float f; unsigned u; } a, b; a.f = f0; b.f = f1;
  return ((a.u + 0x8000u) >> 16) | ((b.u + 0x8000u) & 0xFFFF0000u);
}
static __device__ __forceinline__ float bf2f(unsigned short u) {
  union { unsigned u; float f; } v; v.u = ((unsigned)u) << 16;
  return v.f;
}
static __device__ __forceinline__ bf16x8 ldb(const unsigned short* p) {
  return *(const bf16x8*)p;
}
static __device__ __forceinline__ f32x4 mm(bf16x8 a, bf16x8 b, f32x4 c) {
  return __builtin_amdgcn_mfma_f32_16x16x32_bf16(a, b, c, 0, 0, 0);
}

// ------ Kernel 1: LN -> xn [b][n][c] bf16  (+ fused fp32->bf16 weight cvt) --
__global__ __launch_bounds__(256) void k_lncvt(const float* __restrict__ x,
                                               const float* __restrict__ gamma,
                                               unsigned short* __restrict__ xn,
                                               const float* __restrict__ wq,
                                               const float* __restrict__ wo,
                                               unsigned short* __restrict__ wqb,
                                               unsigned short* __restrict__ wob) {
  int blk = blockIdx.x;
  if (blk >= 256) {                       // weight convert: 256 blocks
    int t = (blk - 256) * 256 + threadIdx.x;
    int e = t * 4;
    if (e < 768 * 256) {
      float4 v = *(const float4*)(wq + e);
      u16x4 pk = { f2bfr(v.x), f2bfr(v.y), f2bfr(v.z), f2bfr(v.w) };
      *(u16x4*)(wqb + e) = pk;
    } else {
      int e2 = e - 768 * 256;
      float4 v = *(const float4*)(wo + e2);
      u16x4 pk = { f2bfr(v.x), f2bfr(v.y), f2bfr(v.z), f2bfr(v.w) };
      *(u16x4*)(wob + e2) = pk;
    }
    return;
  }
  int b  = blk >> 7;
  int n0 = (blk & 127) * 32;
  int t  = threadIdx.x;
  int nl = t & 31;
  int cg = t >> 5;                 // channel group 0..7 (32 channels each)
  int n  = n0 + nl;
  const float* xp = x + ((size_t)(b * CCH + cg * 32)) * NSEQ + n;
  float vals[32];
  float s = 0.f, s2 = 0.f;
#pragma unroll
  for (int j = 0; j < 32; j++) {
    float v = xp[(size_t)j * NSEQ];
    vals[j] = v; s += v; s2 += v * v;
  }
  __shared__ float rs[8][32], rs2[8][32];
  rs[cg][nl] = s; rs2[cg][nl] = s2;
  __syncthreads();
  float S = 0.f, S2 = 0.f;
#pragma unroll
  for (int g = 0; g < 8; g++) { S += rs[g][nl]; S2 += rs2[g][nl]; }
  float mean = S * (1.f / 256.f);
  float var  = S2 * (1.f / 256.f) - mean * mean;
  float rstd = rsqrtf(var + 1e-5f);
  unsigned short* dst = xn + ((size_t)b * NSEQ + n) * CCH + cg * 32;
#pragma unroll
  for (int j0 = 0; j0 < 32; j0 += 8) {
    u16x8 pk;
#pragma unroll
    for (int j = 0; j < 8; j++)
      pk[j] = f2bfr((vals[j0 + j] - mean) * rstd * gamma[cg * 32 + j0 + j]);
    *(u16x8*)(dst + j0) = pk;
  }
}

// --- Kernel 2: QKV GEMM + fused l2norm -------------------------------------
// oi 0..3: q head oi -> qt [b][h][n][d] (scaled by 8*log2e); oi 4..7: k head
// oi-4 -> ktb [b][h][n][d]; oi 8..11: v -> qkv [b][o][n].
__global__ __launch_bounds__(256) void k_qkv(const unsigned short* __restrict__ wqb,
                                             const unsigned short* __restrict__ xn,
                                             unsigned short* __restrict__ qkv,
                                             unsigned short* __restrict__ qt,
                                             unsigned short* __restrict__ ktb) {
  int n0 = blockIdx.x * 64;
  int oi = blockIdx.y;
  int o0 = oi * 64;
  int b  = blockIdx.z;
  __shared__ unsigned short Al[64 * 40];   // [o][c] stride40 (2-way max = free)
  __shared__ unsigned short Bl[64 * 40];   // [n][c]
  __shared__ float sq[2][64];
  int t = threadIdx.x;
  int lane = t & 63, w = t >> 6;
  int c = lane & 15, quad = lane >> 4;
  int wm = w >> 1, wn = w & 1;
  f32x4 acc[2][2] = {};
  int r = t >> 2, seg = (t & 3) * 8;
  const unsigned short* apg = wqb + (size_t)(o0 + r) * CCH + seg;
  const unsigned short* bpg = xn + ((size_t)b * NSEQ + n0 + r) * CCH + seg;
  for (int kt = 0; kt < 8; kt++) {
    if (kt) __syncthreads();
    *(u16x8*)&Al[r * 40 + seg] = *(const u16x8*)(apg + kt * 32);
    *(u16x8*)&Bl[r * 40 + seg] = *(const u16x8*)(bpg + kt * 32);
    __syncthreads();
    bf16x8 a0 = ldb(&Al[(wm * 32      + c) * 40 + quad * 8]);
    bf16x8 a1 = ldb(&Al[(wm * 32 + 16 + c) * 40 + quad * 8]);
    bf16x8 b0 = ldb(&Bl[(wn * 32      + c) * 40 + quad * 8]);
    bf16x8 b1 = ldb(&Bl[(wn * 32 + 16 + c) * 40 + quad * 8]);
    acc[0][0] = mm(a0, b0, acc[0][0]);
    acc[0][1] = mm(a0, b1, acc[0][1]);
    acc[1][0] = mm(a1, b0, acc[1][0]);
    acc[1][1] = mm(a1, b1, acc[1][1]);
  }
  if (oi < 8) {
    // per-n sum of squares: this wave covers d in [wm*32, wm*32+32)
    float s0 = 0.f, s1 = 0.f;
#pragma unroll
    for (int i = 0; i < 2; i++)
#pragma unroll
      for (int rr = 0; rr < 4; rr++) {
        s0 += acc[i][0][rr] * acc[i][0][rr];
        s1 += acc[i][1][rr] * acc[i][1][rr];
      }
    s0 += __shfl_xor(s0, 16); s0 += __shfl_xor(s0, 32);
    s1 += __shfl_xor(s1, 16); s1 += __shfl_xor(s1, 32);
    __syncthreads();
    if (quad == 0) {
      sq[wm][wn * 32 + c]      = s0;
      sq[wm][wn * 32 + 16 + c] = s1;
    }
    __syncthreads();
    float r0 = rsqrtf(sq[0][wn * 32 + c]      + sq[1][wn * 32 + c]      + 1e-12f);
    float r1 = rsqrtf(sq[0][wn * 32 + 16 + c] + sq[1][wn * 32 + 16 + c] + 1e-12f);
    if (oi < 4) { r0 *= 11.541560327111707f; r1 *= 11.541560327111707f; } // 8*log2e
    int h = oi & 3;
    unsigned short* base = (oi < 4 ? qt : ktb) + ((size_t)(b * NH + h) * NSEQ) * DH;
#pragma unroll
    for (int i = 0; i < 2; i++)
#pragma unroll
      for (int j = 0; j < 2; j++) {
        float rsc = j ? r1 : r0;
        int n = n0 + wn * 32 + j * 16 + c;
        int d = wm * 32 + i * 16 + quad * 4;
        uint2 pk = { pack2(acc[i][j][0] * rsc, acc[i][j][1] * rsc),
                     pack2(acc[i][j][2] * rsc, acc[i][j][3] * rsc) };
        *(uint2*)(base + (size_t)n * DH + d) = pk;
      }
  } else {
#pragma unroll
    for (int i = 0; i < 2; i++)
#pragma unroll
      for (int j = 0; j < 2; j++)
#pragma unroll
        for (int rr = 0; rr < 4; rr++) {
          int o = o0 + wm * 32 + i * 16 + quad * 4 + rr;
          int n = n0 + wn * 32 + j * 16 + c;
          qkv[((size_t)b * 768 + o) * NSEQ + n] = f2bfr(acc[i][j][rr]);
        }
  }
}

// ------ Kernel 3: flash attention, max-free softmax, split-KV ---------------
// sim bounded: |q.k|<=1, scale 8 folded as 8*log2e into q -> st in [-11.6,11.6]
// P = exp2(st) raw (<=3100); normalization cancels the missing max-shift.
// l via MFMA with ones-B: accl layout matches acc -> zero shuffles.
__global__ __launch_bounds__(256, 5) void k_attn(
    const unsigned short* __restrict__ qt,
    const unsigned short* __restrict__ ktb,
    const unsigned short* __restrict__ qkv,
    unsigned short* __restrict__ ao,
    unsigned short* __restrict__ opart,
    float* __restrict__ lpart,
    int S, int kvlen) {
  int i0 = blockIdx.x * 64;
  int h  = blockIdx.y;
  int bz = blockIdx.z;
  int b  = bz / S, s = bz % S;
  __shared__ unsigned short Kl[64 * 72];   // [j][d]
  __shared__ unsigned short Vl[64 * 72];   // [d][j]
  __shared__ unsigned short Pl[64 * 72];   // Q staging, then per-wave P [i][j]
  int t = threadIdx.x;
  int lane = t & 63, w = t >> 6;
  int c = lane & 15, quad = lane >> 4;
  int r = t >> 2, seg = (t & 3) * 16;

  const unsigned short* qbase = qt  + ((size_t)(b * NH + h) * NSEQ) * DH;
  const unsigned short* kbase = ktb + ((size_t)(b * NH + h) * NSEQ) * DH;
  const unsigned short* vbase = qkv + ((size_t)b * 768 + 512 + h * 64) * NSEQ;

  {
    const unsigned short* p = qbase + (size_t)(i0 + r) * DH + seg;
    *(u16x8*)&Pl[r * 72 + seg]     = *(const u16x8*)p;
    *(u16x8*)&Pl[r * 72 + seg + 8] = *(const u16x8*)(p + 8);
  }
  __syncthreads();
  bf16x8 qf0 = ldb(&Pl[(w * 16 + c) * 72 + quad * 8]);        // d 0..31
  bf16x8 qf1 = ldb(&Pl[(w * 16 + c) * 72 + 32 + quad * 8]);   // d 32..63
  __syncthreads();

  u16x8 onesu;
#pragma unroll
  for (int j = 0; j < 8; j++) onesu[j] = 0x3F80;               // bf16 1.0
  bf16x8 ones = *(bf16x8*)&onesu;

  f32x4 acc[4] = {};
  f32x4 accl = {};

  const unsigned short* kp = kbase + (size_t)(s * kvlen + r) * DH + seg;
  const unsigned short* vp = vbase + (size_t)r * NSEQ + s * kvlen + seg;
  for (int it = 0; it < kvlen / 64; it++) {
    *(u16x8*)&Kl[r * 72 + seg]     = *(const u16x8*)kp;
    *(u16x8*)&Kl[r * 72 + seg + 8] = *(const u16x8*)(kp + 8);
    *(u16x8*)&Vl[r * 72 + seg]     = *(const u16x8*)vp;
    *(u16x8*)&Vl[r * 72 + seg + 8] = *(const u16x8*)(vp + 8);
    kp += 64 * DH; vp += 64;
    __syncthreads();

    // S^T tile: rows j = jt*16+quad*4+rr, col i = lane&15
#pragma unroll
    for (int jt = 0; jt < 4; jt++) {
      f32x4 z = {};
      z = mm(ldb(&Kl[(jt * 16 + c) * 72 + quad * 8]),      qf0, z);
      z = mm(ldb(&Kl[(jt * 16 + c) * 72 + 32 + quad * 8]), qf1, z);
      // P[i][j] per-wave region: lane i = w*16+c, j = jt*16+quad*4..+4
      uint2 pk = { pack2(exp2f(z[0]), exp2f(z[1])),
                   pack2(exp2f(z[2]), exp2f(z[3])) };
      *(uint2*)&Pl[(w * 16 + c) * 72 + jt * 16 + quad * 4] = pk;
    }
    // intra-wave LDS ordering (write->read same rows) is handled by lgkmcnt
    bf16x8 pa0 = ldb(&Pl[(w * 16 + c) * 72 + quad * 8]);
    bf16x8 pa1 = ldb(&Pl[(w * 16 + c) * 72 + 32 + quad * 8]);
#pragma unroll
    for (int dt = 0; dt < 4; dt++) {
      acc[dt] = mm(pa0, ldb(&Vl[(dt * 16 + c) * 72 + quad * 8]), acc[dt]);
      acc[dt] = mm(pa1, ldb(&Vl[(dt * 16 + c) * 72 + 32 + quad * 8]), acc[dt]);
    }
    accl = mm(pa0, ones, accl);      // row sums -> same (quad,rr) layout as acc
    accl = mm(pa1, ones, accl);
    __syncthreads();                 // protect Kl/Vl for next stage
  }

  if (S > 1) {
    size_t rb = ((size_t)(b * NH + h) * S + s) * NSEQ + i0 + w * 16;
    if (c == 0) {
#pragma unroll
      for (int rr = 0; rr < 4; rr++) lpart[rb + quad * 4 + rr] = accl[rr];
    }
#pragma unroll
    for (int rr = 0; rr < 4; rr++)
#pragma unroll
      for (int dt = 0; dt < 4; dt++)
        opart[(rb + quad * 4 + rr) * 64 + dt * 16 + c] = f2bfr(acc[dt][rr]);
  } else {
#pragma unroll
    for (int rr = 0; rr < 4; rr++) {
      float inv = 1.f / accl[rr];
      int i = i0 + w * 16 + quad * 4 + rr;
#pragma unroll
      for (int dt = 0; dt < 4; dt++)
        ao[((size_t)b * NSEQ + i) * INNER + h * 64 + dt * 16 + c] =
            f2bfr(acc[dt][rr] * inv);
    }
  }
}

// ------ Kernel 3b: merge split-KV partials (plain sums) -> ao bf16 ----------
__global__ __launch_bounds__(256) void k_merge(
    const unsigned short* __restrict__ opart,
    const float* __restrict__ lpart,
    unsigned short* __restrict__ ao, int S) {
  int t = blockIdx.x * 256 + threadIdx.x;     // 131072 threads
  int row = t >> 2;                            // (b*NH+h)*NSEQ + i
  int dseg = (t & 3) * 16;
  int b = row >> 14, rem = row & 16383;
  int h = rem >> 12, i = rem & 4095;

  float l = 0.f;
  float o[16];
#pragma unroll
  for (int j = 0; j < 16; j++) o[j] = 0.f;
  for (int s = 0; s < S; s++) {
    size_t rb = ((size_t)(b * NH + h) * S + s) * NSEQ + i;
    l += lpart[rb];
    const unsigned short* p = opart + rb * 64 + dseg;
    u16x8 v0 = *(const u16x8*)p;
    u16x8 v1 = *(const u16x8*)(p + 8);
#pragma unroll
    for (int j = 0; j < 8; j++) {
      o[j]     += bf2f(v0[j]);
      o[8 + j] += bf2f(v1[j]);
    }
  }
  float inv = 1.f / l;
  unsigned short* dst = ao + ((size_t)b * NSEQ + i) * INNER + h * 64 + dseg;
  uint4 pk0 = { pack2(o[0] * inv, o[1] * inv),  pack2(o[2] * inv, o[3] * inv),
                pack2(o[4] * inv, o[5] * inv),  pack2(o[6] * inv, o[7] * inv) };
  uint4 pk1 = { pack2(o[8] * inv, o[9] * inv),  pack2(o[10] * inv, o[11] * inv),
                pack2(o[12] * inv, o[13] * inv),pack2(o[14] * inv, o[15] * inv) };
  *(uint4*)dst = pk0;
  *(uint4*)(dst + 8) = pk1;
}

// ------ Kernel 4: out-proj + residual: out[b][o][n] = wo*ao + x -------------
__global__ __launch_bounds__(256) void k_out(const unsigned short* __restrict__ wob,
                                             const unsigned short* __restrict__ ao,
                                             const float* __restrict__ x,
                                             float* __restrict__ out) {
  int n0 = blockIdx.x * 64;
  int o0 = blockIdx.y * 64;
  int b  = blockIdx.z;
  __shared__ unsigned short Al[64 * 40];
  __shared__ unsigned short Bl[64 * 40];
  int t = threadIdx.x;
  int lane = t & 63, w = t >> 6;
  int c = lane & 15, quad = lane >> 4;
  int wm = w >> 1, wn = w & 1;
  f32x4 acc[2][2] = {};
  int r = t >> 2, seg = (t & 3) * 8;
  const unsigned short* apg = wob + (size_t)(o0 + r) * INNER + seg;
  const unsigned short* bpg = ao + ((size_t)b * NSEQ + n0 + r) * INNER + seg;
  for (int kt = 0; kt < 8; kt++) {
    if (kt) __syncthreads();
    *(u16x8*)&Al[r * 40 + seg] = *(const u16x8*)(apg + kt * 32);
    *(u16x8*)&Bl[r * 40 + seg] = *(const u16x8*)(bpg + kt * 32);
    __syncthreads();
    bf16x8 a0 = ldb(&Al[(wm * 32      + c) * 40 + quad * 8]);
    bf16x8 a1 = ldb(&Al[(wm * 32 + 16 + c) * 40 + quad * 8]);
    bf16x8 b0 = ldb(&Bl[(wn * 32      + c) * 40 + quad * 8]);
    bf16x8 b1 = ldb(&Bl[(wn * 32 + 16 + c) * 40 + quad * 8]);
    acc[0][0] = mm(a0, b0, acc[0][0]);
    acc[0][1] = mm(a0, b1, acc[0][1]);
    acc[1][0] = mm(a1, b0, acc[1][0]);
    acc[1][1] = mm(a1, b1, acc[1][1]);
  }
#pragma unroll
  for (int i = 0; i < 2; i++)
#pragma unroll
    for (int j = 0; j < 2; j++)
#pragma unroll
      for (int rr = 0; rr < 4; rr++) {
        int o = o0 + wm * 32 + i * 16 + quad * 4 + rr;
        int n = n0 + wn * 32 + j * 16 + c;
        size_t idx = ((size_t)b * CCH + o) * NSEQ + n;
        out[idx] = acc[i][j][rr] + x[idx];
      }
}

extern "C" void kernel_launch(void* const* d_in, const int* in_sizes, int n_in,
                              void* d_out, int out_size, void* d_ws, size_t ws_size,
                              hipStream_t stream) {
  const float* x     = (const float*)d_in[0];
  const float* gamma = (const float*)d_in[1];
  const float* wq    = (const float*)d_in[2];
  const float* wo    = (const float*)d_in[3];
  float* out = (float*)d_out;

  const size_t MB = 1u << 20;
  char* ws = (char*)d_ws;
  // ws layout:
  unsigned short* ao  = (unsigned short*)ws;                   // [0,4)  bf16 [B][N][256]
  unsigned short* xn  = (unsigned short*)(ws + 4 * MB);        // [4,8)  bf16 [B][N][256]
  unsigned short* qkv = (unsigned short*)(ws + 8 * MB);        // [8,20) bf16 [B][768][N] (v region used)
  unsigned short* wqb = (unsigned short*)(ws + 20 * MB);       // 384 KB
  unsigned short* wob = (unsigned short*)(ws + 20 * MB + 512 * 1024); // 128 KB
  unsigned short* qt  = (unsigned short*)(ws + 21 * MB);       // [21,25) bf16 [B][H][N][D]
  unsigned short* ktb = (unsigned short*)(ws + 25 * MB);       // [25,29) bf16 [B][H][N][D]
  unsigned short* opart = (unsigned short*)(ws + 29 * MB);     // S*B*H*N*64 bf16
  int S;
  if (ws_size >= 48 * MB) S = 4;
  else if (ws_size >= 39 * MB) S = 2;
  else S = 1;
  size_t opart_bytes = (size_t)S * BATCH * NH * NSEQ * DH * 2;
  float* lpart = (float*)(ws + 29 * MB + opart_bytes);
  int kvlen = NSEQ / S;

  k_lncvt<<<dim3(512),         256, 0, stream>>>(x, gamma, xn, wq, wo, wqb, wob);
  k_qkv  <<<dim3(64, 12, 2),   256, 0, stream>>>(wqb, xn, qkv, qt, ktb);
  k_attn <<<dim3(64, 4, 2 * S),256, 0, stream>>>(qt, ktb, qkv, ao, opart,
                                                 lpart, S, kvlen);
  if (S > 1)
    k_merge<<<dim3(512), 256, 0, stream>>>(opart, lpart, ao, S);
  k_out  <<<dim3(64, 4, 2),    256, 0, stream>>>(wob, ao, x, out);
}

// Round 4
// 150.777 us; speedup vs baseline: 1.5973x; 1.0200x over previous
//
#include <hip/hip_runtime.h>

// Problem: B=2, C=256, F*H*W=N=4096, heads=4, dim_head=64, inner=256
#define BATCH 2
#define CCH   256
#define NSEQ  4096
#define NH    4
#define DH    64
#define INNER 256

typedef __attribute__((ext_vector_type(8))) __bf16 bf16x8;
typedef __attribute__((ext_vector_type(4))) float f32x4;
typedef __attribute__((ext_vector_type(8))) unsigned short u16x8;
typedef __attribute__((ext_vector_type(4))) unsigned short u16x4;

// async global->LDS, 16B per lane; LDS dest = wave-uniform base + lane*16
#define GLD16(gsrc, ldst)                                                     \
  __builtin_amdgcn_global_load_lds(                                           \
      (const __attribute__((address_space(1))) unsigned int*)(const void*)(gsrc), \
      (__attribute__((address_space(3))) unsigned int*)(void*)(ldst), 16, 0, 0)

// round-half-up bf16 (inputs finite; <=0.5ulp bias vs RNE, irrelevant here)
static __device__ __forceinline__ unsigned short f2bfr(float f) {
  union { float f; unsigned u; } v; v.f = f;
  return (unsigned short)((v.u + 0x8000u) >> 16);
}
// pack two floats -> bf16 pair (low = f0) via v_perm_b32: 3 VALU ops
static __device__ __forceinline__ unsigned pack2(float f0, float f1) {
  union { float f; unsigned u; } a, b; a.f = f0; b.f = f1;
  return __builtin_amdgcn_perm(b.u + 0x8000u, a.u + 0x8000u, 0x07060302u);
}
static __device__ __forceinline__ float bf2f(unsigned short u) {
  union { unsigned u; float f; } v; v.u = ((unsigned)u) << 16;
  return v.f;
}
static __device__ __forceinline__ bf16x8 ldb(const unsigned short* p) {
  return *(const bf16x8*)p;
}
static __device__ __forceinline__ f32x4 mm(bf16x8 a, bf16x8 b, f32x4 c) {
  return __builtin_amdgcn_mfma_f32_16x16x32_bf16(a, b, c, 0, 0, 0);
}

// ------ Kernel 1: LN -> xn [b][n][c] bf16  (+ fused fp32->bf16 weight cvt) --
__global__ __launch_bounds__(256) void k_lncvt(const float* __restrict__ x,
                                               const float* __restrict__ gamma,
                                               unsigned short* __restrict__ xn,
                                               const float* __restrict__ wq,
                                               const float* __restrict__ wo,
                                               unsigned short* __restrict__ wqb,
                                               unsigned short* __restrict__ wob) {
  int blk = blockIdx.x;
  if (blk >= 256) {                       // weight convert: 256 blocks
    int t = (blk - 256) * 256 + threadIdx.x;
    int e = t * 4;
    if (e < 768 * 256) {
      float4 v = *(const float4*)(wq + e);
      u16x4 pk = { f2bfr(v.x), f2bfr(v.y), f2bfr(v.z), f2bfr(v.w) };
      *(u16x4*)(wqb + e) = pk;
    } else {
      int e2 = e - 768 * 256;
      float4 v = *(const float4*)(wo + e2);
      u16x4 pk = { f2bfr(v.x), f2bfr(v.y), f2bfr(v.z), f2bfr(v.w) };
      *(u16x4*)(wob + e2) = pk;
    }
    return;
  }
  int b  = blk >> 7;
  int n0 = (blk & 127) * 32;
  int t  = threadIdx.x;
  int nl = t & 31;
  int cg = t >> 5;                 // channel group 0..7 (32 channels each)
  int n  = n0 + nl;
  const float* xp = x + ((size_t)(b * CCH + cg * 32)) * NSEQ + n;
  float vals[32];
  float s = 0.f, s2 = 0.f;
#pragma unroll
  for (int j = 0; j < 32; j++) {
    float v = xp[(size_t)j * NSEQ];
    vals[j] = v; s += v; s2 += v * v;
  }
  __shared__ float rs[8][32], rs2[8][32];
  rs[cg][nl] = s; rs2[cg][nl] = s2;
  __syncthreads();
  float S = 0.f, S2 = 0.f;
#pragma unroll
  for (int g = 0; g < 8; g++) { S += rs[g][nl]; S2 += rs2[g][nl]; }
  float mean = S * (1.f / 256.f);
  float var  = S2 * (1.f / 256.f) - mean * mean;
  float rstd = rsqrtf(var + 1e-5f);
  unsigned short* dst = xn + ((size_t)b * NSEQ + n) * CCH + cg * 32;
#pragma unroll
  for (int j0 = 0; j0 < 32; j0 += 8) {
    u16x8 pk;
#pragma unroll
    for (int j = 0; j < 8; j++)
      pk[j] = f2bfr((vals[j0 + j] - mean) * rstd * gamma[cg * 32 + j0 + j]);
    *(u16x8*)(dst + j0) = pk;
  }
}

// --- Kernel 2: QKV GEMM + fused l2norm -------------------------------------
// Tiles staged via global_load_lds into stride-32 rows with XOR chunk swizzle
// (phys_chunk = logical_chunk ^ (row&3); 8-elem chunks).
// oi 0..3: q head oi -> qt (scaled 8*log2e); 4..7: k -> ktb; 8..11: v -> qkv.
__global__ __launch_bounds__(256) void k_qkv(const unsigned short* __restrict__ wqb,
                                             const unsigned short* __restrict__ xn,
                                             unsigned short* __restrict__ qkv,
                                             unsigned short* __restrict__ qt,
                                             unsigned short* __restrict__ ktb) {
  int n0 = blockIdx.x * 64;
  int oi = blockIdx.y;
  int o0 = oi * 64;
  int b  = blockIdx.z;
  __shared__ unsigned short Al[64 * 32];   // [o][c] swizzled
  __shared__ unsigned short Bl[64 * 32];   // [n][c] swizzled
  __shared__ float sq[2][64];
  int t = threadIdx.x;
  int lane = t & 63, w = t >> 6;
  int c = lane & 15, quad = lane >> 4;
  int wm = w >> 1, wn = w & 1;
  f32x4 acc[2][2] = {};
  // staging: lane covers row w*16 + (lane>>2), phys chunk lane&3
  int srow = w * 16 + (lane >> 2);
  int ssw  = ((lane & 3) ^ ((lane >> 2) & 3)) * 8;   // swizzled src elem off
  const unsigned short* apg = wqb + (size_t)(o0 + srow) * CCH + ssw;
  const unsigned short* bpg = xn + ((size_t)b * NSEQ + n0 + srow) * CCH + ssw;
  unsigned short* al = Al + w * 16 * 32;   // wave-uniform LDS base
  unsigned short* bl = Bl + w * 16 * 32;
  int swq = (quad ^ (c & 3)) * 8;          // ds_read swizzled chunk
  for (int kt = 0; kt < 8; kt++) {
    if (kt) __syncthreads();
    GLD16(apg + kt * 32, al);
    GLD16(bpg + kt * 32, bl);
    __syncthreads();
    bf16x8 a0 = ldb(&Al[(wm * 32      + c) * 32 + swq]);
    bf16x8 a1 = ldb(&Al[(wm * 32 + 16 + c) * 32 + swq]);
    bf16x8 b0 = ldb(&Bl[(wn * 32      + c) * 32 + swq]);
    bf16x8 b1 = ldb(&Bl[(wn * 32 + 16 + c) * 32 + swq]);
    acc[0][0] = mm(a0, b0, acc[0][0]);
    acc[0][1] = mm(a0, b1, acc[0][1]);
    acc[1][0] = mm(a1, b0, acc[1][0]);
    acc[1][1] = mm(a1, b1, acc[1][1]);
  }
  if (oi < 8) {
    // per-n sum of squares: this wave covers d in [wm*32, wm*32+32)
    float s0 = 0.f, s1 = 0.f;
#pragma unroll
    for (int i = 0; i < 2; i++)
#pragma unroll
      for (int rr = 0; rr < 4; rr++) {
        s0 += acc[i][0][rr] * acc[i][0][rr];
        s1 += acc[i][1][rr] * acc[i][1][rr];
      }
    s0 += __shfl_xor(s0, 16); s0 += __shfl_xor(s0, 32);
    s1 += __shfl_xor(s1, 16); s1 += __shfl_xor(s1, 32);
    __syncthreads();
    if (quad == 0) {
      sq[wm][wn * 32 + c]      = s0;
      sq[wm][wn * 32 + 16 + c] = s1;
    }
    __syncthreads();
    float r0 = rsqrtf(sq[0][wn * 32 + c]      + sq[1][wn * 32 + c]      + 1e-12f);
    float r1 = rsqrtf(sq[0][wn * 32 + 16 + c] + sq[1][wn * 32 + 16 + c] + 1e-12f);
    if (oi < 4) { r0 *= 11.541560327111707f; r1 *= 11.541560327111707f; } // 8*log2e
    int h = oi & 3;
    unsigned short* base = (oi < 4 ? qt : ktb) + ((size_t)(b * NH + h) * NSEQ) * DH;
#pragma unroll
    for (int i = 0; i < 2; i++)
#pragma unroll
      for (int j = 0; j < 2; j++) {
        float rsc = j ? r1 : r0;
        int n = n0 + wn * 32 + j * 16 + c;
        int d = wm * 32 + i * 16 + quad * 4;
        uint2 pk = { pack2(acc[i][j][0] * rsc, acc[i][j][1] * rsc),
                     pack2(acc[i][j][2] * rsc, acc[i][j][3] * rsc) };
        *(uint2*)(base + (size_t)n * DH + d) = pk;
      }
  } else {
#pragma unroll
    for (int i = 0; i < 2; i++)
#pragma unroll
      for (int j = 0; j < 2; j++)
#pragma unroll
        for (int rr = 0; rr < 4; rr++) {
          int o = o0 + wm * 32 + i * 16 + quad * 4 + rr;
          int n = n0 + wn * 32 + j * 16 + c;
          qkv[((size_t)b * 768 + o) * NSEQ + n] = f2bfr(acc[i][j][rr]);
        }
  }
}

// ------ Kernel 3: flash attention, max-free softmax, split-KV ---------------
// K/V staged via global_load_lds into stride-64 rows with XOR chunk swizzle
// (phys_chunk = logical_chunk ^ (row&7); 8-elem chunks). P padded stride-72.
__global__ __launch_bounds__(256, 6) void k_attn(
    const unsigned short* __restrict__ qt,
    const unsigned short* __restrict__ ktb,
    const unsigned short* __restrict__ qkv,
    unsigned short* __restrict__ ao,
    unsigned short* __restrict__ opart,
    float* __restrict__ lpart,
    int S, int kvlen) {
  int i0 = blockIdx.x * 64;
  int h  = blockIdx.y;
  int bz = blockIdx.z;
  int b  = bz / S, s = bz % S;
  __shared__ unsigned short Kl[64 * 64];   // [j][d] swizzled
  __shared__ unsigned short Vl[64 * 64];   // [d][j] swizzled
  __shared__ unsigned short Pl[64 * 72];   // Q staging, then per-wave P [i][j]
  int t = threadIdx.x;
  int lane = t & 63, w = t >> 6;
  int c = lane & 15, quad = lane >> 4;
  int r = t >> 2, seg = (t & 3) * 16;

  const unsigned short* qbase = qt  + ((size_t)(b * NH + h) * NSEQ) * DH;
  const unsigned short* kbase = ktb + ((size_t)(b * NH + h) * NSEQ) * DH;
  const unsigned short* vbase = qkv + ((size_t)b * 768 + 512 + h * 64) * NSEQ;

  {
    const unsigned short* p = qbase + (size_t)(i0 + r) * DH + seg;
    *(u16x8*)&Pl[r * 72 + seg]     = *(const u16x8*)p;
    *(u16x8*)&Pl[r * 72 + seg + 8] = *(const u16x8*)(p + 8);
  }
  __syncthreads();
  bf16x8 qf0 = ldb(&Pl[(w * 16 + c) * 72 + quad * 8]);        // d 0..31
  bf16x8 qf1 = ldb(&Pl[(w * 16 + c) * 72 + 32 + quad * 8]);   // d 32..63
  __syncthreads();

  u16x8 onesu;
#pragma unroll
  for (int j = 0; j < 8; j++) onesu[j] = 0x3F80;               // bf16 1.0
  bf16x8 ones = *(bf16x8*)&onesu;

  f32x4 acc[4] = {};
  f32x4 accl = {};

  // staging: lane covers row w*16 + 8i + (lane>>3), phys chunk lane&7
  int lr = lane >> 3, lc = lane & 7;
  int ssw = (lc ^ lr) * 8;                 // swizzled source elem offset
  const unsigned short* kp = kbase + (size_t)(s * kvlen + w * 16 + lr) * DH + ssw;
  const unsigned short* vp = vbase + (size_t)(w * 16 + lr) * NSEQ + s * kvlen + ssw;
  unsigned short* kl0 = Kl + (w * 16)     * 64;   // wave-uniform LDS bases
  unsigned short* kl1 = Kl + (w * 16 + 8) * 64;
  unsigned short* vl0 = Vl + (w * 16)     * 64;
  unsigned short* vl1 = Vl + (w * 16 + 8) * 64;
  // ds_read swizzled chunk offsets (logical quad / quad+4)
  int sw0 = (quad ^ (c & 7)) * 8;
  int sw1 = sw0 ^ 32;

  for (int it = 0; it < kvlen / 64; it++) {
    GLD16(kp,             kl0);
    GLD16(kp + 8 * DH,    kl1);
    GLD16(vp,             vl0);
    GLD16(vp + 8 * NSEQ,  vl1);
    kp += 64 * DH; vp += 64;
    __syncthreads();

    // S^T tile: rows j = jt*16+quad*4+rr, col i = lane&15
#pragma unroll
    for (int jt = 0; jt < 4; jt++) {
      f32x4 z = {};
      z = mm(ldb(&Kl[(jt * 16 + c) * 64 + sw0]), qf0, z);
      z = mm(ldb(&Kl[(jt * 16 + c) * 64 + sw1]), qf1, z);
      // P[i][j] per-wave region: lane i = w*16+c, j = jt*16+quad*4..+4
      uint2 pk = { pack2(exp2f(z[0]), exp2f(z[1])),
                   pack2(exp2f(z[2]), exp2f(z[3])) };
      *(uint2*)&Pl[(w * 16 + c) * 72 + jt * 16 + quad * 4] = pk;
    }
    bf16x8 pa0 = ldb(&Pl[(w * 16 + c) * 72 + quad * 8]);
    bf16x8 pa1 = ldb(&Pl[(w * 16 + c) * 72 + 32 + quad * 8]);
#pragma unroll
    for (int dt = 0; dt < 4; dt++) {
      acc[dt] = mm(pa0, ldb(&Vl[(dt * 16 + c) * 64 + sw0]), acc[dt]);
      acc[dt] = mm(pa1, ldb(&Vl[(dt * 16 + c) * 64 + sw1]), acc[dt]);
    }
    accl = mm(pa0, ones, accl);      // row sums -> same (quad,rr) layout as acc
    accl = mm(pa1, ones, accl);
    __syncthreads();                 // protect Kl/Vl for next stage
  }

  if (S > 1) {
    size_t rb = ((size_t)(b * NH + h) * S + s) * NSEQ + i0 + w * 16;
    if (c == 0) {
#pragma unroll
      for (int rr = 0; rr < 4; rr++) lpart[rb + quad * 4 + rr] = accl[rr];
    }
#pragma unroll
    for (int rr = 0; rr < 4; rr++)
#pragma unroll
      for (int dt = 0; dt < 4; dt++)
        opart[(rb + quad * 4 + rr) * 64 + dt * 16 + c] = f2bfr(acc[dt][rr]);
  } else {
#pragma unroll
    for (int rr = 0; rr < 4; rr++) {
      float inv = 1.f / accl[rr];
      int i = i0 + w * 16 + quad * 4 + rr;
#pragma unroll
      for (int dt = 0; dt < 4; dt++)
        ao[((size_t)b * NSEQ + i) * INNER + h * 64 + dt * 16 + c] =
            f2bfr(acc[dt][rr] * inv);
    }
  }
}

// ------ Kernel 3b: merge split-KV partials (plain sums) -> ao bf16 ----------
__global__ __launch_bounds__(256) void k_merge(
    const unsigned short* __restrict__ opart,
    const float* __restrict__ lpart,
    unsigned short* __restrict__ ao, int S) {
  int t = blockIdx.x * 256 + threadIdx.x;     // 131072 threads
  int row = t >> 2;                            // (b*NH+h)*NSEQ + i
  int dseg = (t & 3) * 16;
  int b = row >> 14, rem = row & 16383;
  int h = rem >> 12, i = rem & 4095;

  float l = 0.f;
  float o[16];
#pragma unroll
  for (int j = 0; j < 16; j++) o[j] = 0.f;
  for (int s = 0; s < S; s++) {
    size_t rb = ((size_t)(b * NH + h) * S + s) * NSEQ + i;
    l += lpart[rb];
    const unsigned short* p = opart + rb * 64 + dseg;
    u16x8 v0 = *(const u16x8*)p;
    u16x8 v1 = *(const u16x8*)(p + 8);
#pragma unroll
    for (int j = 0; j < 8; j++) {
      o[j]     += bf2f(v0[j]);
      o[8 + j] += bf2f(v1[j]);
    }
  }
  float inv = 1.f / l;
  unsigned short* dst = ao + ((size_t)b * NSEQ + i) * INNER + h * 64 + dseg;
  uint4 pk0 = { pack2(o[0] * inv, o[1] * inv),  pack2(o[2] * inv, o[3] * inv),
                pack2(o[4] * inv, o[5] * inv),  pack2(o[6] * inv, o[7] * inv) };
  uint4 pk1 = { pack2(o[8] * inv, o[9] * inv),  pack2(o[10] * inv, o[11] * inv),
                pack2(o[12] * inv, o[13] * inv),pack2(o[14] * inv, o[15] * inv) };
  *(uint4*)dst = pk0;
  *(uint4*)(dst + 8) = pk1;
}

// ------ Kernel 4: out-proj + residual: out[b][o][n] = wo*ao + x -------------
__global__ __launch_bounds__(256) void k_out(const unsigned short* __restrict__ wob,
                                             const unsigned short* __restrict__ ao,
                                             const float* __restrict__ x,
                                             float* __restrict__ out) {
  int n0 = blockIdx.x * 64;
  int o0 = blockIdx.y * 64;
  int b  = blockIdx.z;
  __shared__ unsigned short Al[64 * 32];
  __shared__ unsigned short Bl[64 * 32];
  int t = threadIdx.x;
  int lane = t & 63, w = t >> 6;
  int c = lane & 15, quad = lane >> 4;
  int wm = w >> 1, wn = w & 1;
  f32x4 acc[2][2] = {};
  int srow = w * 16 + (lane >> 2);
  int ssw  = ((lane & 3) ^ ((lane >> 2) & 3)) * 8;
  const unsigned short* apg = wob + (size_t)(o0 + srow) * INNER + ssw;
  const unsigned short* bpg = ao + ((size_t)b * NSEQ + n0 + srow) * INNER + ssw;
  unsigned short* al = Al + w * 16 * 32;
  unsigned short* bl = Bl + w * 16 * 32;
  int swq = (quad ^ (c & 3)) * 8;
  for (int kt = 0; kt < 8; kt++) {
    if (kt) __syncthreads();
    GLD16(apg + kt * 32, al);
    GLD16(bpg + kt * 32, bl);
    __syncthreads();
    bf16x8 a0 = ldb(&Al[(wm * 32      + c) * 32 + swq]);
    bf16x8 a1 = ldb(&Al[(wm * 32 + 16 + c) * 32 + swq]);
    bf16x8 b0 = ldb(&Bl[(wn * 32      + c) * 32 + swq]);
    bf16x8 b1 = ldb(&Bl[(wn * 32 + 16 + c) * 32 + swq]);
    acc[0][0] = mm(a0, b0, acc[0][0]);
    acc[0][1] = mm(a0, b1, acc[0][1]);
    acc[1][0] = mm(a1, b0, acc[1][0]);
    acc[1][1] = mm(a1, b1, acc[1][1]);
  }
#pragma unroll
  for (int i = 0; i < 2; i++)
#pragma unroll
    for (int j = 0; j < 2; j++)
#pragma unroll
      for (int rr = 0; rr < 4; rr++) {
        int o = o0 + wm * 32 + i * 16 + quad * 4 + rr;
        int n = n0 + wn * 32 + j * 16 + c;
        size_t idx = ((size_t)b * CCH + o) * NSEQ + n;
        out[idx] = acc[i][j][rr] + x[idx];
      }
}

extern "C" void kernel_launch(void* const* d_in, const int* in_sizes, int n_in,
                              void* d_out, int out_size, void* d_ws, size_t ws_size,
                              hipStream_t stream) {
  const float* x     = (const float*)d_in[0];
  const float* gamma = (const float*)d_in[1];
  const float* wq    = (const float*)d_in[2];
  const float* wo    = (const float*)d_in[3];
  float* out = (float*)d_out;

  const size_t MB = 1u << 20;
  char* ws = (char*)d_ws;
  // ws layout:
  unsigned short* ao  = (unsigned short*)ws;                   // [0,4)  bf16 [B][N][256]
  unsigned short* xn  = (unsigned short*)(ws + 4 * MB);        // [4,8)  bf16 [B][N][256]
  unsigned short* qkv = (unsigned short*)(ws + 8 * MB);        // [8,20) bf16 [B][768][N] (v region used)
  unsigned short* wqb = (unsigned short*)(ws + 20 * MB);       // 384 KB
  unsigned short* wob = (unsigned short*)(ws + 20 * MB + 512 * 1024); // 128 KB
  unsigned short* qt  = (unsigned short*)(ws + 21 * MB);       // [21,25) bf16 [B][H][N][D]
  unsigned short* ktb = (unsigned short*)(ws + 25 * MB);       // [25,29) bf16 [B][H][N][D]
  unsigned short* opart = (unsigned short*)(ws + 29 * MB);     // S*B*H*N*64 bf16
  int S;
  if (ws_size >= 48 * MB) S = 4;
  else if (ws_size >= 39 * MB) S = 2;
  else S = 1;
  size_t opart_bytes = (size_t)S * BATCH * NH * NSEQ * DH * 2;
  float* lpart = (float*)(ws + 29 * MB + opart_bytes);
  int kvlen = NSEQ / S;

  k_lncvt<<<dim3(512),         256, 0, stream>>>(x, gamma, xn, wq, wo, wqb, wob);
  k_qkv  <<<dim3(64, 12, 2),   256, 0, stream>>>(wqb, xn, qkv, qt, ktb);
  k_attn <<<dim3(64, 4, 2 * S),256, 0, stream>>>(qt, ktb, qkv, ao, opart,
                                                 lpart, S, kvlen);
  if (S > 1)
    k_merge<<<dim3(512), 256, 0, stream>>>(opart, lpart, ao, S);
  k_out  <<<dim3(64, 4, 2),    256, 0, stream>>>(wob, ao, x, out);
}

// Round 5
// 148.725 us; speedup vs baseline: 1.6194x; 1.0138x over previous
//
#include <hip/hip_runtime.h>

// Problem: B=2, C=256, F*H*W=N=4096, heads=4, dim_head=64, inner=256
#define BATCH 2
#define CCH   256
#define NSEQ  4096
#define NH    4
#define DH    64
#define INNER 256

typedef __attribute__((ext_vector_type(8))) __bf16 bf16x8;
typedef __attribute__((ext_vector_type(4))) float f32x4;
typedef __attribute__((ext_vector_type(8))) unsigned short u16x8;
typedef __attribute__((ext_vector_type(4))) unsigned short u16x4;

// async global->LDS, 16B per lane; LDS dest = wave-uniform base + lane*16
#define GLD16(gsrc, ldst)                                                     \
  __builtin_amdgcn_global_load_lds(                                           \
      (const __attribute__((address_space(1))) unsigned int*)(const void*)(gsrc), \
      (__attribute__((address_space(3))) unsigned int*)(void*)(ldst), 16, 0, 0)

// round-half-up bf16 (inputs finite; <=0.5ulp bias vs RNE, irrelevant here)
static __device__ __forceinline__ unsigned short f2bfr(float f) {
  union { float f; unsigned u; } v; v.f = f;
  return (unsigned short)((v.u + 0x8000u) >> 16);
}
// pack two floats -> bf16 pair (low = f0) via v_perm_b32: 3 VALU ops
static __device__ __forceinline__ unsigned pack2(float f0, float f1) {
  union { float f; unsigned u; } a, b; a.f = f0; b.f = f1;
  return __builtin_amdgcn_perm(b.u + 0x8000u, a.u + 0x8000u, 0x07060302u);
}
static __device__ __forceinline__ float bf2f(unsigned short u) {
  union { unsigned u; float f; } v; v.u = ((unsigned)u) << 16;
  return v.f;
}
static __device__ __forceinline__ bf16x8 ldb(const unsigned short* p) {
  return *(const bf16x8*)p;
}
static __device__ __forceinline__ f32x4 mm(bf16x8 a, bf16x8 b, f32x4 c) {
  return __builtin_amdgcn_mfma_f32_16x16x32_bf16(a, b, c, 0, 0, 0);
}

// ------ Kernel 1: LN -> xn [b][n][c] bf16  (+ fused fp32->bf16 weight cvt) --
__global__ __launch_bounds__(256) void k_lncvt(const float* __restrict__ x,
                                               const float* __restrict__ gamma,
                                               unsigned short* __restrict__ xn,
                                               const float* __restrict__ wq,
                                               const float* __restrict__ wo,
                                               unsigned short* __restrict__ wqb,
                                               unsigned short* __restrict__ wob) {
  int blk = blockIdx.x;
  if (blk >= 256) {                       // weight convert: 256 blocks
    int t = (blk - 256) * 256 + threadIdx.x;
    int e = t * 4;
    if (e < 768 * 256) {
      float4 v = *(const float4*)(wq + e);
      u16x4 pk = { f2bfr(v.x), f2bfr(v.y), f2bfr(v.z), f2bfr(v.w) };
      *(u16x4*)(wqb + e) = pk;
    } else {
      int e2 = e - 768 * 256;
      float4 v = *(const float4*)(wo + e2);
      u16x4 pk = { f2bfr(v.x), f2bfr(v.y), f2bfr(v.z), f2bfr(v.w) };
      *(u16x4*)(wob + e2) = pk;
    }
    return;
  }
  int b  = blk >> 7;
  int n0 = (blk & 127) * 32;
  int t  = threadIdx.x;
  int nl = t & 31;
  int cg = t >> 5;                 // channel group 0..7 (32 channels each)
  int n  = n0 + nl;
  const float* xp = x + ((size_t)(b * CCH + cg * 32)) * NSEQ + n;
  float vals[32];
  float s = 0.f, s2 = 0.f;
#pragma unroll
  for (int j = 0; j < 32; j++) {
    float v = xp[(size_t)j * NSEQ];
    vals[j] = v; s += v; s2 += v * v;
  }
  __shared__ float rs[8][32], rs2[8][32];
  rs[cg][nl] = s; rs2[cg][nl] = s2;
  __syncthreads();
  float S = 0.f, S2 = 0.f;
#pragma unroll
  for (int g = 0; g < 8; g++) { S += rs[g][nl]; S2 += rs2[g][nl]; }
  float mean = S * (1.f / 256.f);
  float var  = S2 * (1.f / 256.f) - mean * mean;
  float rstd = rsqrtf(var + 1e-5f);
  unsigned short* dst = xn + ((size_t)b * NSEQ + n) * CCH + cg * 32;
#pragma unroll
  for (int j0 = 0; j0 < 32; j0 += 8) {
    u16x8 pk;
#pragma unroll
    for (int j = 0; j < 8; j++)
      pk[j] = f2bfr((vals[j0 + j] - mean) * rstd * gamma[cg * 32 + j0 + j]);
    *(u16x8*)(dst + j0) = pk;
  }
}

// --- Kernel 2: QKV GEMM + fused l2norm, BK=128 (3 barriers total) ----------
// Tiles staged via global_load_lds into stride-128 rows, XOR chunk swizzle
// (phys_chunk = logical_chunk ^ (row&7); 8-elem chunks; 2-way bank = free).
// oi 0..3: q head oi -> qt (scaled 8*log2e); 4..7: k -> ktb; 8..11: v -> qkv.
__global__ __launch_bounds__(256) void k_qkv(const unsigned short* __restrict__ wqb,
                                             const unsigned short* __restrict__ xn,
                                             unsigned short* __restrict__ qkv,
                                             unsigned short* __restrict__ qt,
                                             unsigned short* __restrict__ ktb) {
  int n0 = blockIdx.x * 64;
  int oi = blockIdx.y;
  int o0 = oi * 64;
  int b  = blockIdx.z;
  __shared__ unsigned short Al[64 * 128];   // [o][k-local] swizzled, 16 KB
  __shared__ unsigned short Bl[64 * 128];   // [n][k-local] swizzled, 16 KB
  int t = threadIdx.x;
  int lane = t & 63, w = t >> 6;
  int c = lane & 15, quad = lane >> 4;
  int wm = w >> 1, wn = w & 1;
  f32x4 acc[2][2] = {};
  // staging: wave w covers rows [w*16,w*16+16); call q covers 4 rows
  int lr = lane >> 4;                       // row within 4-row group
  int lchk = lane & 15;                     // phys chunk (16 chunks/row)
  const unsigned short* apg = wqb + (size_t)o0 * CCH;
  const unsigned short* bpg = xn + ((size_t)b * NSEQ + n0) * CCH;
  for (int kt = 0; kt < 2; kt++) {
    if (kt) __syncthreads();
#pragma unroll
    for (int q = 0; q < 4; q++) {
      int r = w * 16 + q * 4 + lr;
      int srcoff = r * CCH + kt * 128 + ((lchk ^ (r & 7)) * 8);
      unsigned short* ldst = (w * 16 + q * 4) * 128 + (unsigned short*)0;
      GLD16(apg + srcoff, Al + (size_t)(w * 16 + q * 4) * 128);
      GLD16(bpg + srcoff, Bl + (size_t)(w * 16 + q * 4) * 128);
      (void)ldst;
    }
    __syncthreads();
#pragma unroll
    for (int ks = 0; ks < 4; ks++) {
      int ra0 = wm * 32 + c, ra1 = ra0 + 16;
      int rb0 = wn * 32 + c, rb1 = rb0 + 16;
      bf16x8 a0 = ldb(&Al[ra0 * 128 + (((ks * 4 + quad) ^ (ra0 & 7)) * 8)]);
      bf16x8 a1 = ldb(&Al[ra1 * 128 + (((ks * 4 + quad) ^ (ra1 & 7)) * 8)]);
      bf16x8 b0 = ldb(&Bl[rb0 * 128 + (((ks * 4 + quad) ^ (rb0 & 7)) * 8)]);
      bf16x8 b1 = ldb(&Bl[rb1 * 128 + (((ks * 4 + quad) ^ (rb1 & 7)) * 8)]);
      acc[0][0] = mm(a0, b0, acc[0][0]);
      acc[0][1] = mm(a0, b1, acc[0][1]);
      acc[1][0] = mm(a1, b0, acc[1][0]);
      acc[1][1] = mm(a1, b1, acc[1][1]);
    }
  }
  if (oi < 8) {
    // per-n sum of squares: this wave covers d in [wm*32, wm*32+32)
    float* sq = (float*)Al;                 // reuse Al after final reads
    float s0 = 0.f, s1 = 0.f;
#pragma unroll
    for (int i = 0; i < 2; i++)
#pragma unroll
      for (int rr = 0; rr < 4; rr++) {
        s0 += acc[i][0][rr] * acc[i][0][rr];
        s1 += acc[i][1][rr] * acc[i][1][rr];
      }
    s0 += __shfl_xor(s0, 16); s0 += __shfl_xor(s0, 32);
    s1 += __shfl_xor(s1, 16); s1 += __shfl_xor(s1, 32);
    __syncthreads();
    if (quad == 0) {
      sq[wm * 64 + wn * 32 + c]      = s0;
      sq[wm * 64 + wn * 32 + 16 + c] = s1;
    }
    __syncthreads();
    float r0 = rsqrtf(sq[wn * 32 + c]      + sq[64 + wn * 32 + c]      + 1e-12f);
    float r1 = rsqrtf(sq[wn * 32 + 16 + c] + sq[64 + wn * 32 + 16 + c] + 1e-12f);
    if (oi < 4) { r0 *= 11.541560327111707f; r1 *= 11.541560327111707f; } // 8*log2e
    int h = oi & 3;
    unsigned short* base = (oi < 4 ? qt : ktb) + ((size_t)(b * NH + h) * NSEQ) * DH;
#pragma unroll
    for (int i = 0; i < 2; i++)
#pragma unroll
      for (int j = 0; j < 2; j++) {
        float rsc = j ? r1 : r0;
        int n = n0 + wn * 32 + j * 16 + c;
        int d = wm * 32 + i * 16 + quad * 4;
        uint2 pk = { pack2(acc[i][j][0] * rsc, acc[i][j][1] * rsc),
                     pack2(acc[i][j][2] * rsc, acc[i][j][3] * rsc) };
        *(uint2*)(base + (size_t)n * DH + d) = pk;
      }
  } else {
#pragma unroll
    for (int i = 0; i < 2; i++)
#pragma unroll
      for (int j = 0; j < 2; j++)
#pragma unroll
        for (int rr = 0; rr < 4; rr++) {
          int o = o0 + wm * 32 + i * 16 + quad * 4 + rr;
          int n = n0 + wn * 32 + j * 16 + c;
          qkv[((size_t)b * 768 + o) * NSEQ + n] = f2bfr(acc[i][j][rr]);
        }
  }
}

// ------ Kernel 3: flash attention, max-free softmax, split-KV ---------------
// K/V staged via global_load_lds into stride-64 rows with XOR chunk swizzle
// (phys_chunk = logical_chunk ^ (row&7); 8-elem chunks). P padded stride-72.
__global__ __launch_bounds__(256, 6) void k_attn(
    const unsigned short* __restrict__ qt,
    const unsigned short* __restrict__ ktb,
    const unsigned short* __restrict__ qkv,
    unsigned short* __restrict__ ao,
    unsigned short* __restrict__ opart,
    float* __restrict__ lpart,
    int S, int kvlen) {
  int i0 = blockIdx.x * 64;
  int h  = blockIdx.y;
  int bz = blockIdx.z;
  int b  = bz / S, s = bz % S;
  __shared__ unsigned short Kl[64 * 64];   // [j][d] swizzled
  __shared__ unsigned short Vl[64 * 64];   // [d][j] swizzled
  __shared__ unsigned short Pl[64 * 72];   // Q staging, then per-wave P [i][j]
  int t = threadIdx.x;
  int lane = t & 63, w = t >> 6;
  int c = lane & 15, quad = lane >> 4;
  int r = t >> 2, seg = (t & 3) * 16;

  const unsigned short* qbase = qt  + ((size_t)(b * NH + h) * NSEQ) * DH;
  const unsigned short* kbase = ktb + ((size_t)(b * NH + h) * NSEQ) * DH;
  const unsigned short* vbase = qkv + ((size_t)b * 768 + 512 + h * 64) * NSEQ;

  {
    const unsigned short* p = qbase + (size_t)(i0 + r) * DH + seg;
    *(u16x8*)&Pl[r * 72 + seg]     = *(const u16x8*)p;
    *(u16x8*)&Pl[r * 72 + seg + 8] = *(const u16x8*)(p + 8);
  }
  __syncthreads();
  bf16x8 qf0 = ldb(&Pl[(w * 16 + c) * 72 + quad * 8]);        // d 0..31
  bf16x8 qf1 = ldb(&Pl[(w * 16 + c) * 72 + 32 + quad * 8]);   // d 32..63
  __syncthreads();

  u16x8 onesu;
#pragma unroll
  for (int j = 0; j < 8; j++) onesu[j] = 0x3F80;               // bf16 1.0
  bf16x8 ones = *(bf16x8*)&onesu;

  f32x4 acc[4] = {};
  f32x4 accl = {};

  // staging: lane covers row w*16 + 8i + (lane>>3), phys chunk lane&7
  int lr = lane >> 3, lc = lane & 7;
  int ssw = (lc ^ lr) * 8;                 // swizzled source elem offset
  const unsigned short* kp = kbase + (size_t)(s * kvlen + w * 16 + lr) * DH + ssw;
  const unsigned short* vp = vbase + (size_t)(w * 16 + lr) * NSEQ + s * kvlen + ssw;
  unsigned short* kl0 = Kl + (w * 16)     * 64;   // wave-uniform LDS bases
  unsigned short* kl1 = Kl + (w * 16 + 8) * 64;
  unsigned short* vl0 = Vl + (w * 16)     * 64;
  unsigned short* vl1 = Vl + (w * 16 + 8) * 64;
  // ds_read swizzled chunk offsets (logical quad / quad+4)
  int sw0 = (quad ^ (c & 7)) * 8;
  int sw1 = sw0 ^ 32;

  for (int it = 0; it < kvlen / 64; it++) {
    GLD16(kp,             kl0);
    GLD16(kp + 8 * DH,    kl1);
    GLD16(vp,             vl0);
    GLD16(vp + 8 * NSEQ,  vl1);
    kp += 64 * DH; vp += 64;
    __syncthreads();

    // S^T tile: rows j = jt*16+quad*4+rr, col i = lane&15
#pragma unroll
    for (int jt = 0; jt < 4; jt++) {
      f32x4 z = {};
      z = mm(ldb(&Kl[(jt * 16 + c) * 64 + sw0]), qf0, z);
      z = mm(ldb(&Kl[(jt * 16 + c) * 64 + sw1]), qf1, z);
      // P[i][j] per-wave region: lane i = w*16+c, j = jt*16+quad*4..+4
      uint2 pk = { pack2(exp2f(z[0]), exp2f(z[1])),
                   pack2(exp2f(z[2]), exp2f(z[3])) };
      *(uint2*)&Pl[(w * 16 + c) * 72 + jt * 16 + quad * 4] = pk;
    }
    bf16x8 pa0 = ldb(&Pl[(w * 16 + c) * 72 + quad * 8]);
    bf16x8 pa1 = ldb(&Pl[(w * 16 + c) * 72 + 32 + quad * 8]);
#pragma unroll
    for (int dt = 0; dt < 4; dt++) {
      acc[dt] = mm(pa0, ldb(&Vl[(dt * 16 + c) * 64 + sw0]), acc[dt]);
      acc[dt] = mm(pa1, ldb(&Vl[(dt * 16 + c) * 64 + sw1]), acc[dt]);
    }
    accl = mm(pa0, ones, accl);      // row sums -> same (quad,rr) layout as acc
    accl = mm(pa1, ones, accl);
    __syncthreads();                 // protect Kl/Vl for next stage
  }

  if (S > 1) {
    size_t rb = ((size_t)(b * NH + h) * S + s) * NSEQ + i0 + w * 16;
    if (c == 0) {
#pragma unroll
      for (int rr = 0; rr < 4; rr++) lpart[rb + quad * 4 + rr] = accl[rr];
    }
#pragma unroll
    for (int rr = 0; rr < 4; rr++)
#pragma unroll
      for (int dt = 0; dt < 4; dt++)
        opart[(rb + quad * 4 + rr) * 64 + dt * 16 + c] = f2bfr(acc[dt][rr]);
  } else {
#pragma unroll
    for (int rr = 0; rr < 4; rr++) {
      float inv = 1.f / accl[rr];
      int i = i0 + w * 16 + quad * 4 + rr;
#pragma unroll
      for (int dt = 0; dt < 4; dt++)
        ao[((size_t)b * NSEQ + i) * INNER + h * 64 + dt * 16 + c] =
            f2bfr(acc[dt][rr] * inv);
    }
  }
}

// ------ Kernel 3b: merge split-KV partials (plain sums) -> ao bf16 ----------
__global__ __launch_bounds__(256) void k_merge(
    const unsigned short* __restrict__ opart,
    const float* __restrict__ lpart,
    unsigned short* __restrict__ ao, int S) {
  int t = blockIdx.x * 256 + threadIdx.x;     // 131072 threads
  int row = t >> 2;                            // (b*NH+h)*NSEQ + i
  int dseg = (t & 3) * 16;
  int b = row >> 14, rem = row & 16383;
  int h = rem >> 12, i = rem & 4095;

  float l = 0.f;
  float o[16];
#pragma unroll
  for (int j = 0; j < 16; j++) o[j] = 0.f;
  for (int s = 0; s < S; s++) {
    size_t rb = ((size_t)(b * NH + h) * S + s) * NSEQ + i;
    l += lpart[rb];
    const unsigned short* p = opart + rb * 64 + dseg;
    u16x8 v0 = *(const u16x8*)p;
    u16x8 v1 = *(const u16x8*)(p + 8);
#pragma unroll
    for (int j = 0; j < 8; j++) {
      o[j]     += bf2f(v0[j]);
      o[8 + j] += bf2f(v1[j]);
    }
  }
  float inv = 1.f / l;
  unsigned short* dst = ao + ((size_t)b * NSEQ + i) * INNER + h * 64 + dseg;
  uint4 pk0 = { pack2(o[0] * inv, o[1] * inv),  pack2(o[2] * inv, o[3] * inv),
                pack2(o[4] * inv, o[5] * inv),  pack2(o[6] * inv, o[7] * inv) };
  uint4 pk1 = { pack2(o[8] * inv, o[9] * inv),  pack2(o[10] * inv, o[11] * inv),
                pack2(o[12] * inv, o[13] * inv),pack2(o[14] * inv, o[15] * inv) };
  *(uint4*)dst = pk0;
  *(uint4*)(dst + 8) = pk1;
}

// ------ Kernel 4: out-proj + residual, BK=128 (3 barriers total) ------------
__global__ __launch_bounds__(256) void k_out(const unsigned short* __restrict__ wob,
                                             const unsigned short* __restrict__ ao,
                                             const float* __restrict__ x,
                                             float* __restrict__ out) {
  int n0 = blockIdx.x * 64;
  int o0 = blockIdx.y * 64;
  int b  = blockIdx.z;
  __shared__ unsigned short Al[64 * 128];
  __shared__ unsigned short Bl[64 * 128];
  int t = threadIdx.x;
  int lane = t & 63, w = t >> 6;
  int c = lane & 15, quad = lane >> 4;
  int wm = w >> 1, wn = w & 1;
  f32x4 acc[2][2] = {};
  int lr = lane >> 4;
  int lchk = lane & 15;
  const unsigned short* apg = wob + (size_t)o0 * INNER;
  const unsigned short* bpg = ao + ((size_t)b * NSEQ + n0) * INNER;
  for (int kt = 0; kt < 2; kt++) {
    if (kt) __syncthreads();
#pragma unroll
    for (int q = 0; q < 4; q++) {
      int r = w * 16 + q * 4 + lr;
      int srcoff = r * INNER + kt * 128 + ((lchk ^ (r & 7)) * 8);
      GLD16(apg + srcoff, Al + (size_t)(w * 16 + q * 4) * 128);
      GLD16(bpg + srcoff, Bl + (size_t)(w * 16 + q * 4) * 128);
    }
    __syncthreads();
#pragma unroll
    for (int ks = 0; ks < 4; ks++) {
      int ra0 = wm * 32 + c, ra1 = ra0 + 16;
      int rb0 = wn * 32 + c, rb1 = rb0 + 16;
      bf16x8 a0 = ldb(&Al[ra0 * 128 + (((ks * 4 + quad) ^ (ra0 & 7)) * 8)]);
      bf16x8 a1 = ldb(&Al[ra1 * 128 + (((ks * 4 + quad) ^ (ra1 & 7)) * 8)]);
      bf16x8 b0 = ldb(&Bl[rb0 * 128 + (((ks * 4 + quad) ^ (rb0 & 7)) * 8)]);
      bf16x8 b1 = ldb(&Bl[rb1 * 128 + (((ks * 4 + quad) ^ (rb1 & 7)) * 8)]);
      acc[0][0] = mm(a0, b0, acc[0][0]);
      acc[0][1] = mm(a0, b1, acc[0][1]);
      acc[1][0] = mm(a1, b0, acc[1][0]);
      acc[1][1] = mm(a1, b1, acc[1][1]);
    }
  }
#pragma unroll
  for (int i = 0; i < 2; i++)
#pragma unroll
    for (int j = 0; j < 2; j++)
#pragma unroll
      for (int rr = 0; rr < 4; rr++) {
        int o = o0 + wm * 32 + i * 16 + quad * 4 + rr;
        int n = n0 + wn * 32 + j * 16 + c;
        size_t idx = ((size_t)b * CCH + o) * NSEQ + n;
        out[idx] = acc[i][j][rr] + x[idx];
      }
}

extern "C" void kernel_launch(void* const* d_in, const int* in_sizes, int n_in,
                              void* d_out, int out_size, void* d_ws, size_t ws_size,
                              hipStream_t stream) {
  const float* x     = (const float*)d_in[0];
  const float* gamma = (const float*)d_in[1];
  const float* wq    = (const float*)d_in[2];
  const float* wo    = (const float*)d_in[3];
  float* out = (float*)d_out;

  const size_t MB = 1u << 20;
  char* ws = (char*)d_ws;
  // ws layout:
  unsigned short* ao  = (unsigned short*)ws;                   // [0,4)  bf16 [B][N][256]
  unsigned short* xn  = (unsigned short*)(ws + 4 * MB);        // [4,8)  bf16 [B][N][256]
  unsigned short* qkv = (unsigned short*)(ws + 8 * MB);        // [8,20) bf16 [B][768][N] (v region used)
  unsigned short* wqb = (unsigned short*)(ws + 20 * MB);       // 384 KB
  unsigned short* wob = (unsigned short*)(ws + 20 * MB + 512 * 1024); // 128 KB
  unsigned short* qt  = (unsigned short*)(ws + 21 * MB);       // [21,25) bf16 [B][H][N][D]
  unsigned short* ktb = (unsigned short*)(ws + 25 * MB);       // [25,29) bf16 [B][H][N][D]
  unsigned short* opart = (unsigned short*)(ws + 29 * MB);     // S*B*H*N*64 bf16
  int S;
  if (ws_size >= 48 * MB) S = 4;
  else if (ws_size >= 39 * MB) S = 2;
  else S = 1;
  size_t opart_bytes = (size_t)S * BATCH * NH * NSEQ * DH * 2;
  float* lpart = (float*)(ws + 29 * MB + opart_bytes);
  int kvlen = NSEQ / S;

  k_lncvt<<<dim3(512),         256, 0, stream>>>(x, gamma, xn, wq, wo, wqb, wob);
  k_qkv  <<<dim3(64, 12, 2),   256, 0, stream>>>(wqb, xn, qkv, qt, ktb);
  k_attn <<<dim3(64, 4, 2 * S),256, 0, stream>>>(qt, ktb, qkv, ao, opart,
                                                 lpart, S, kvlen);
  if (S > 1)
    k_merge<<<dim3(512), 256, 0, stream>>>(opart, lpart, ao, S);
  k_out  <<<dim3(64, 4, 2),    256, 0, stream>>>(wob, ao, x, out);
}

// Round 6
// 148.649 us; speedup vs baseline: 1.6202x; 1.0005x over previous
//
#include <hip/hip_runtime.h>

// Problem: B=2, C=256, F*H*W=N=4096, heads=4, dim_head=64, inner=256
#define BATCH 2
#define CCH   256
#define NSEQ  4096
#define NH    4
#define DH    64
#define INNER 256

typedef __attribute__((ext_vector_type(8))) __bf16 bf16x8;
typedef __attribute__((ext_vector_type(4))) float f32x4;
typedef __attribute__((ext_vector_type(8))) unsigned short u16x8;
typedef __attribute__((ext_vector_type(4))) unsigned short u16x4;

// async global->LDS, 16B per lane; LDS dest = wave-uniform base + lane*16
#define GLD16(gsrc, ldst)                                                     \
  __builtin_amdgcn_global_load_lds(                                           \
      (const __attribute__((address_space(1))) unsigned int*)(const void*)(gsrc), \
      (__attribute__((address_space(3))) unsigned int*)(void*)(ldst), 16, 0, 0)

// round-half-up bf16 (inputs finite; <=0.5ulp bias vs RNE, irrelevant here)
static __device__ __forceinline__ unsigned short f2bfr(float f) {
  union { float f; unsigned u; } v; v.f = f;
  return (unsigned short)((v.u + 0x8000u) >> 16);
}
// pack two floats -> bf16 pair (low = f0) via v_perm_b32: 3 VALU ops
static __device__ __forceinline__ unsigned pack2(float f0, float f1) {
  union { float f; unsigned u; } a, b; a.f = f0; b.f = f1;
  return __builtin_amdgcn_perm(b.u + 0x8000u, a.u + 0x8000u, 0x07060302u);
}
static __device__ __forceinline__ float bf2f(unsigned short u) {
  union { unsigned u; float f; } v; v.u = ((unsigned)u) << 16;
  return v.f;
}
static __device__ __forceinline__ bf16x8 ldb(const unsigned short* p) {
  return *(const bf16x8*)p;
}
static __device__ __forceinline__ f32x4 mm(bf16x8 a, bf16x8 b, f32x4 c) {
  return __builtin_amdgcn_mfma_f32_16x16x32_bf16(a, b, c, 0, 0, 0);
}

// ------ Kernel 1: LN -> xn [b][n][c] bf16  (+ fused fp32->bf16 weight cvt) --
__global__ __launch_bounds__(256) void k_lncvt(const float* __restrict__ x,
                                               const float* __restrict__ gamma,
                                               unsigned short* __restrict__ xn,
                                               const float* __restrict__ wq,
                                               const float* __restrict__ wo,
                                               unsigned short* __restrict__ wqb,
                                               unsigned short* __restrict__ wob) {
  int blk = blockIdx.x;
  if (blk >= 256) {                       // weight convert: 256 blocks
    int t = (blk - 256) * 256 + threadIdx.x;
    int e = t * 4;
    if (e < 768 * 256) {
      float4 v = *(const float4*)(wq + e);
      u16x4 pk = { f2bfr(v.x), f2bfr(v.y), f2bfr(v.z), f2bfr(v.w) };
      *(u16x4*)(wqb + e) = pk;
    } else {
      int e2 = e - 768 * 256;
      float4 v = *(const float4*)(wo + e2);
      u16x4 pk = { f2bfr(v.x), f2bfr(v.y), f2bfr(v.z), f2bfr(v.w) };
      *(u16x4*)(wob + e2) = pk;
    }
    return;
  }
  int b  = blk >> 7;
  int n0 = (blk & 127) * 32;
  int t  = threadIdx.x;
  int nl = t & 31;
  int cg = t >> 5;                 // channel group 0..7 (32 channels each)
  int n  = n0 + nl;
  const float* xp = x + ((size_t)(b * CCH + cg * 32)) * NSEQ + n;
  float vals[32];
  float s = 0.f, s2 = 0.f;
#pragma unroll
  for (int j = 0; j < 32; j++) {
    float v = xp[(size_t)j * NSEQ];
    vals[j] = v; s += v; s2 += v * v;
  }
  __shared__ float rs[8][32], rs2[8][32];
  rs[cg][nl] = s; rs2[cg][nl] = s2;
  __syncthreads();
  float S = 0.f, S2 = 0.f;
#pragma unroll
  for (int g = 0; g < 8; g++) { S += rs[g][nl]; S2 += rs2[g][nl]; }
  float mean = S * (1.f / 256.f);
  float var  = S2 * (1.f / 256.f) - mean * mean;
  float rstd = rsqrtf(var + 1e-5f);
  unsigned short* dst = xn + ((size_t)b * NSEQ + n) * CCH + cg * 32;
#pragma unroll
  for (int j0 = 0; j0 < 32; j0 += 8) {
    u16x8 pk;
#pragma unroll
    for (int j = 0; j < 8; j++)
      pk[j] = f2bfr((vals[j0 + j] - mean) * rstd * gamma[cg * 32 + j0 + j]);
    *(u16x8*)(dst + j0) = pk;
  }
}

// --- Kernel 2: QKV GEMM + fused l2norm, BK=128 (3 barriers total) ----------
// Tiles staged via global_load_lds into stride-128 rows, XOR chunk swizzle.
// oi 0..3: q head oi -> qt (scaled 8*log2e); 4..7: k -> ktb; 8..11: v -> qkv.
__global__ __launch_bounds__(256) void k_qkv(const unsigned short* __restrict__ wqb,
                                             const unsigned short* __restrict__ xn,
                                             unsigned short* __restrict__ qkv,
                                             unsigned short* __restrict__ qt,
                                             unsigned short* __restrict__ ktb) {
  int n0 = blockIdx.x * 64;
  int oi = blockIdx.y;
  int o0 = oi * 64;
  int b  = blockIdx.z;
  __shared__ unsigned short Al[64 * 128];   // [o][k-local] swizzled, 16 KB
  __shared__ unsigned short Bl[64 * 128];   // [n][k-local] swizzled, 16 KB
  int t = threadIdx.x;
  int lane = t & 63, w = t >> 6;
  int c = lane & 15, quad = lane >> 4;
  int wm = w >> 1, wn = w & 1;
  f32x4 acc[2][2] = {};
  int lr = lane >> 4;                       // row within 4-row group
  int lchk = lane & 15;                     // phys chunk (16 chunks/row)
  const unsigned short* apg = wqb + (size_t)o0 * CCH;
  const unsigned short* bpg = xn + ((size_t)b * NSEQ + n0) * CCH;
  for (int kt = 0; kt < 2; kt++) {
    if (kt) __syncthreads();
#pragma unroll
    for (int q = 0; q < 4; q++) {
      int r = w * 16 + q * 4 + lr;
      int srcoff = r * CCH + kt * 128 + ((lchk ^ (r & 7)) * 8);
      GLD16(apg + srcoff, Al + (size_t)(w * 16 + q * 4) * 128);
      GLD16(bpg + srcoff, Bl + (size_t)(w * 16 + q * 4) * 128);
    }
    __syncthreads();
#pragma unroll
    for (int ks = 0; ks < 4; ks++) {
      int ra0 = wm * 32 + c, ra1 = ra0 + 16;
      int rb0 = wn * 32 + c, rb1 = rb0 + 16;
      bf16x8 a0 = ldb(&Al[ra0 * 128 + (((ks * 4 + quad) ^ (ra0 & 7)) * 8)]);
      bf16x8 a1 = ldb(&Al[ra1 * 128 + (((ks * 4 + quad) ^ (ra1 & 7)) * 8)]);
      bf16x8 b0 = ldb(&Bl[rb0 * 128 + (((ks * 4 + quad) ^ (rb0 & 7)) * 8)]);
      bf16x8 b1 = ldb(&Bl[rb1 * 128 + (((ks * 4 + quad) ^ (rb1 & 7)) * 8)]);
      acc[0][0] = mm(a0, b0, acc[0][0]);
      acc[0][1] = mm(a0, b1, acc[0][1]);
      acc[1][0] = mm(a1, b0, acc[1][0]);
      acc[1][1] = mm(a1, b1, acc[1][1]);
    }
  }
  if (oi < 8) {
    // per-n sum of squares: this wave covers d in [wm*32, wm*32+32)
    float* sq = (float*)Al;                 // reuse Al after final reads
    float s0 = 0.f, s1 = 0.f;
#pragma unroll
    for (int i = 0; i < 2; i++)
#pragma unroll
      for (int rr = 0; rr < 4; rr++) {
        s0 += acc[i][0][rr] * acc[i][0][rr];
        s1 += acc[i][1][rr] * acc[i][1][rr];
      }
    s0 += __shfl_xor(s0, 16); s0 += __shfl_xor(s0, 32);
    s1 += __shfl_xor(s1, 16); s1 += __shfl_xor(s1, 32);
    __syncthreads();
    if (quad == 0) {
      sq[wm * 64 + wn * 32 + c]      = s0;
      sq[wm * 64 + wn * 32 + 16 + c] = s1;
    }
    __syncthreads();
    float r0 = rsqrtf(sq[wn * 32 + c]      + sq[64 + wn * 32 + c]      + 1e-12f);
    float r1 = rsqrtf(sq[wn * 32 + 16 + c] + sq[64 + wn * 32 + 16 + c] + 1e-12f);
    if (oi < 4) { r0 *= 11.541560327111707f; r1 *= 11.541560327111707f; } // 8*log2e
    int h = oi & 3;
    unsigned short* base = (oi < 4 ? qt : ktb) + ((size_t)(b * NH + h) * NSEQ) * DH;
#pragma unroll
    for (int i = 0; i < 2; i++)
#pragma unroll
      for (int j = 0; j < 2; j++) {
        float rsc = j ? r1 : r0;
        int n = n0 + wn * 32 + j * 16 + c;
        int d = wm * 32 + i * 16 + quad * 4;
        uint2 pk = { pack2(acc[i][j][0] * rsc, acc[i][j][1] * rsc),
                     pack2(acc[i][j][2] * rsc, acc[i][j][3] * rsc) };
        *(uint2*)(base + (size_t)n * DH + d) = pk;
      }
  } else {
#pragma unroll
    for (int i = 0; i < 2; i++)
#pragma unroll
      for (int j = 0; j < 2; j++)
#pragma unroll
        for (int rr = 0; rr < 4; rr++) {
          int o = o0 + wm * 32 + i * 16 + quad * 4 + rr;
          int n = n0 + wn * 32 + j * 16 + c;
          qkv[((size_t)b * 768 + o) * NSEQ + n] = f2bfr(acc[i][j][rr]);
        }
  }
}

// ------ Kernel 3: flash attention, Q-tile 128 (32 q-rows/wave) --------------
// Max-free softmax (|sim|<=8 folded as 8*log2e into q), split-KV, always
// writes unnormalized opart + row-sum lpart. K/V LDS fragments read once,
// used for both register Q-sets -> ~halved LDS-pipe pressure per output.
__global__ __launch_bounds__(256, 4) void k_attn(
    const unsigned short* __restrict__ qt,
    const unsigned short* __restrict__ ktb,
    const unsigned short* __restrict__ qkv,
    unsigned short* __restrict__ opart,
    float* __restrict__ lpart,
    int S, int kvlen) {
  int i0 = blockIdx.x * 128;
  int h  = blockIdx.y;
  int bz = blockIdx.z;
  int b  = bz / S, s = bz % S;
  __shared__ unsigned short Kl[64 * 64];    // [j][d] swizzled, 8 KB
  __shared__ unsigned short Vl[64 * 64];    // [d][j] swizzled, 8 KB
  __shared__ unsigned short Pl[128 * 64];   // per-wave P [i][j] swizzled, 16 KB
  int t = threadIdx.x;
  int lane = t & 63, w = t >> 6;
  int c = lane & 15, quad = lane >> 4;

  const unsigned short* qbase = qt  + ((size_t)(b * NH + h) * NSEQ) * DH;
  const unsigned short* kbase = ktb + ((size_t)(b * NH + h) * NSEQ) * DH;
  const unsigned short* vbase = qkv + ((size_t)b * 768 + 512 + h * 64) * NSEQ;

  // Q fragments straight from global (one-time, L2-served)
  int rlo = w * 32 + c, rhi = rlo + 16;     // local q-rows of this lane
  const unsigned short* qlo = qbase + (size_t)(i0 + rlo) * DH + quad * 8;
  const unsigned short* qhi = qlo + 16 * DH;
  bf16x8 qlo0 = ldb(qlo), qlo1 = ldb(qlo + 32);
  bf16x8 qhi0 = ldb(qhi), qhi1 = ldb(qhi + 32);

  u16x8 onesu;
#pragma unroll
  for (int j = 0; j < 8; j++) onesu[j] = 0x3F80;               // bf16 1.0
  bf16x8 ones = *(bf16x8*)&onesu;

  f32x4 acclo[4] = {}, acchi[4] = {};
  f32x4 accllo = {}, acclhi = {};

  // K/V staging: lane covers row w*16 + {0,8} + (lane>>3), phys chunk lane&7
  int slr = lane >> 3, slc = lane & 7;
  int ssw = (slc ^ slr) * 8;                // swizzled source elem offset
  const unsigned short* kp = kbase + (size_t)(s * kvlen + w * 16 + slr) * DH + ssw;
  const unsigned short* vp = vbase + (size_t)(w * 16 + slr) * NSEQ + s * kvlen + ssw;
  unsigned short* kl0 = Kl + (w * 16)     * 64;
  unsigned short* kl1 = Kl + (w * 16 + 8) * 64;
  unsigned short* vl0 = Vl + (w * 16)     * 64;
  unsigned short* vl1 = Vl + (w * 16 + 8) * 64;
  int sw0 = (quad ^ (c & 7)) * 8;           // ds_read swizzled chunk offsets
  int sw1 = sw0 ^ 32;
  int r7 = rlo & 7;                         // == rhi & 7

  for (int it = 0; it < kvlen / 64; it++) {
    GLD16(kp,            kl0);
    GLD16(kp + 8 * DH,   kl1);
    GLD16(vp,            vl0);
    GLD16(vp + 8 * NSEQ, vl1);
    kp += 64 * DH; vp += 64;
    __syncthreads();

    // S^T tiles for both q-sets; exp2 + pack + P-write consumed per jt
#pragma unroll
    for (int jt = 0; jt < 4; jt++) {
      bf16x8 k0 = ldb(&Kl[(jt * 16 + c) * 64 + sw0]);
      bf16x8 k1 = ldb(&Kl[(jt * 16 + c) * 64 + sw1]);
      f32x4 zl = {}; zl = mm(k0, qlo0, zl); zl = mm(k1, qlo1, zl);
      f32x4 zh = {}; zh = mm(k0, qhi0, zh); zh = mm(k1, qhi1, zh);
      int cj = jt * 2 + (quad >> 1);        // logical 8-elem chunk
      int sub = (quad & 1) * 4;
      uint2 pkl = { pack2(exp2f(zl[0]), exp2f(zl[1])),
                    pack2(exp2f(zl[2]), exp2f(zl[3])) };
      *(uint2*)&Pl[rlo * 64 + ((cj ^ r7) * 8) + sub] = pkl;
      uint2 pkh = { pack2(exp2f(zh[0]), exp2f(zh[1])),
                    pack2(exp2f(zh[2]), exp2f(zh[3])) };
      *(uint2*)&Pl[rhi * 64 + ((cj ^ r7) * 8) + sub] = pkh;
    }
    // P reads (same-wave rows; lgkmcnt orders write->read)
    bf16x8 plo0 = ldb(&Pl[rlo * 64 + ((quad ^ r7) * 8)]);
    bf16x8 plo1 = ldb(&Pl[rlo * 64 + (((quad + 4) ^ r7) * 8)]);
    bf16x8 phi0 = ldb(&Pl[rhi * 64 + ((quad ^ r7) * 8)]);
    bf16x8 phi1 = ldb(&Pl[rhi * 64 + (((quad + 4) ^ r7) * 8)]);
#pragma unroll
    for (int dt = 0; dt < 4; dt++) {
      bf16x8 v0 = ldb(&Vl[(dt * 16 + c) * 64 + sw0]);
      bf16x8 v1 = ldb(&Vl[(dt * 16 + c) * 64 + sw1]);
      acclo[dt] = mm(plo0, v0, acclo[dt]);
      acclo[dt] = mm(plo1, v1, acclo[dt]);
      acchi[dt] = mm(phi0, v0, acchi[dt]);
      acchi[dt] = mm(phi1, v1, acchi[dt]);
    }
    accllo = mm(plo0, ones, accllo); accllo = mm(plo1, ones, accllo);
    acclhi = mm(phi0, ones, acclhi); acclhi = mm(phi1, ones, acclhi);
    __syncthreads();                 // protect Kl/Vl for next stage
  }

  size_t rb = ((size_t)(b * NH + h) * S + s) * NSEQ + i0 + w * 32;
  if (c == 0) {
#pragma unroll
    for (int rr = 0; rr < 4; rr++) {
      lpart[rb + quad * 4 + rr]      = accllo[rr];
      lpart[rb + 16 + quad * 4 + rr] = acclhi[rr];
    }
  }
#pragma unroll
  for (int rr = 0; rr < 4; rr++)
#pragma unroll
    for (int dt = 0; dt < 4; dt++) {
      opart[(rb + quad * 4 + rr) * 64 + dt * 16 + c]      = f2bfr(acclo[dt][rr]);
      opart[(rb + 16 + quad * 4 + rr) * 64 + dt * 16 + c] = f2bfr(acchi[dt][rr]);
    }
}

// ------ Kernel 4: out-proj + residual, with fused split-KV merge ------------
// B-tile staged by merging opart/lpart inline (bf16 pack -> swizzled LDS).
__global__ __launch_bounds__(256) void k_out(const unsigned short* __restrict__ wob,
                                             const unsigned short* __restrict__ opart,
                                             const float* __restrict__ lpart,
                                             const float* __restrict__ x,
                                             float* __restrict__ out, int S) {
  int n0 = blockIdx.x * 64;
  int o0 = blockIdx.y * 64;
  int b  = blockIdx.z;
  __shared__ unsigned short Al[64 * 128];
  __shared__ unsigned short Bl[64 * 128];
  int t = threadIdx.x;
  int lane = t & 63, w = t >> 6;
  int c = lane & 15, quad = lane >> 4;
  int wm = w >> 1, wn = w & 1;
  f32x4 acc[2][2] = {};
  int lr = lane >> 4;
  int lchk = lane & 15;
  const unsigned short* apg = wob + (size_t)o0 * INNER;
  int br = t >> 2;                         // B row 0..63
  int n  = n0 + br;
  for (int kt = 0; kt < 2; kt++) {
    if (kt) __syncthreads();
#pragma unroll
    for (int q = 0; q < 4; q++) {
      int r = w * 16 + q * 4 + lr;
      int srcoff = r * INNER + kt * 128 + ((lchk ^ (r & 7)) * 8);
      GLD16(apg + srcoff, Al + (size_t)(w * 16 + q * 4) * 128);
    }
    // B staging: merge split-KV partials for k-window [kt*128, kt*128+128)
    float linv[2];
#pragma unroll
    for (int hh = 0; hh < 2; hh++) {
      int h = kt * 2 + hh;
      float l = 0.f;
      for (int s = 0; s < S; s++)
        l += lpart[((size_t)(b * NH + h) * S + s) * NSEQ + n];
      linv[hh] = 1.f / l;
    }
#pragma unroll
    for (int q = 0; q < 4; q++) {
      int cj = (t & 3) + 4 * q;            // logical chunk 0..15
      int hh = cj >> 3;
      int h  = kt * 2 + hh;
      int d  = (cj & 7) * 8;
      float o[8] = {};
      for (int s = 0; s < S; s++) {
        const unsigned short* p =
            opart + (((size_t)(b * NH + h) * S + s) * NSEQ + n) * 64 + d;
        u16x8 v = *(const u16x8*)p;
#pragma unroll
        for (int j = 0; j < 8; j++) o[j] += bf2f(v[j]);
      }
      float iv = linv[hh];
      uint4 pk = { pack2(o[0] * iv, o[1] * iv), pack2(o[2] * iv, o[3] * iv),
                   pack2(o[4] * iv, o[5] * iv), pack2(o[6] * iv, o[7] * iv) };
      *(uint4*)&Bl[br * 128 + ((cj ^ (br & 7)) * 8)] = pk;
    }
    __syncthreads();
#pragma unroll
    for (int ks = 0; ks < 4; ks++) {
      int ra0 = wm * 32 + c, ra1 = ra0 + 16;
      int rb0 = wn * 32 + c, rb1 = rb0 + 16;
      bf16x8 a0 = ldb(&Al[ra0 * 128 + (((ks * 4 + quad) ^ (ra0 & 7)) * 8)]);
      bf16x8 a1 = ldb(&Al[ra1 * 128 + (((ks * 4 + quad) ^ (ra1 & 7)) * 8)]);
      bf16x8 b0 = ldb(&Bl[rb0 * 128 + (((ks * 4 + quad) ^ (rb0 & 7)) * 8)]);
      bf16x8 b1 = ldb(&Bl[rb1 * 128 + (((ks * 4 + quad) ^ (rb1 & 7)) * 8)]);
      acc[0][0] = mm(a0, b0, acc[0][0]);
      acc[0][1] = mm(a0, b1, acc[0][1]);
      acc[1][0] = mm(a1, b0, acc[1][0]);
      acc[1][1] = mm(a1, b1, acc[1][1]);
    }
  }
#pragma unroll
  for (int i = 0; i < 2; i++)
#pragma unroll
    for (int j = 0; j < 2; j++)
#pragma unroll
      for (int rr = 0; rr < 4; rr++) {
        int o = o0 + wm * 32 + i * 16 + quad * 4 + rr;
        int nn = n0 + wn * 32 + j * 16 + c;
        size_t idx = ((size_t)b * CCH + o) * NSEQ + nn;
        out[idx] = acc[i][j][rr] + x[idx];
      }
}

extern "C" void kernel_launch(void* const* d_in, const int* in_sizes, int n_in,
                              void* d_out, int out_size, void* d_ws, size_t ws_size,
                              hipStream_t stream) {
  const float* x     = (const float*)d_in[0];
  const float* gamma = (const float*)d_in[1];
  const float* wq    = (const float*)d_in[2];
  const float* wo    = (const float*)d_in[3];
  float* out = (float*)d_out;

  const size_t MB = 1u << 20;
  char* ws = (char*)d_ws;
  // ws layout:
  unsigned short* xn  = (unsigned short*)ws;                   // [0,4)  bf16 [B][N][256]
  unsigned short* qkv = (unsigned short*)(ws + 4 * MB);        // [4,16) bf16 [B][768][N] (v region used)
  unsigned short* wqb = (unsigned short*)(ws + 16 * MB);       // 384 KB
  unsigned short* wob = (unsigned short*)(ws + 16 * MB + 512 * 1024); // 128 KB
  unsigned short* qt  = (unsigned short*)(ws + 17 * MB);       // [17,21) bf16 [B][H][N][D]
  unsigned short* ktb = (unsigned short*)(ws + 21 * MB);       // [21,25) bf16 [B][H][N][D]
  unsigned short* opart = (unsigned short*)(ws + 25 * MB);     // S*B*H*N*64 bf16
  int S;
  if (ws_size >= 45 * MB) S = 4;
  else if (ws_size >= 36 * MB) S = 2;
  else S = 1;
  size_t opart_bytes = (size_t)S * BATCH * NH * NSEQ * DH * 2;
  float* lpart = (float*)(ws + 25 * MB + opart_bytes);
  int kvlen = NSEQ / S;

  k_lncvt<<<dim3(512),          256, 0, stream>>>(x, gamma, xn, wq, wo, wqb, wob);
  k_qkv  <<<dim3(64, 12, 2),    256, 0, stream>>>(wqb, xn, qkv, qt, ktb);
  k_attn <<<dim3(32, 4, 2 * S), 256, 0, stream>>>(qt, ktb, qkv, opart,
                                                  lpart, S, kvlen);
  k_out  <<<dim3(64, 4, 2),     256, 0, stream>>>(wob, opart, lpart, x, out, S);
}

// Round 7
// 145.511 us; speedup vs baseline: 1.6551x; 1.0216x over previous
//
#include <hip/hip_runtime.h>

// Problem: B=2, C=256, F*H*W=N=4096, heads=4, dim_head=64, inner=256
#define BATCH 2
#define CCH   256
#define NSEQ  4096
#define NH    4
#define DH    64
#define INNER 256

typedef __attribute__((ext_vector_type(8))) __bf16 bf16x8;
typedef __attribute__((ext_vector_type(4))) float f32x4;
typedef __attribute__((ext_vector_type(8))) unsigned short u16x8;
typedef __attribute__((ext_vector_type(4))) unsigned short u16x4;

// async global->LDS, 16B per lane; LDS dest = wave-uniform base + lane*16
#define GLD16(gsrc, ldst)                                                     \
  __builtin_amdgcn_global_load_lds(                                           \
      (const __attribute__((address_space(1))) unsigned int*)(const void*)(gsrc), \
      (__attribute__((address_space(3))) unsigned int*)(void*)(ldst), 16, 0, 0)

// round-half-up bf16 (inputs finite; <=0.5ulp bias vs RNE, irrelevant here)
static __device__ __forceinline__ unsigned short f2bfr(float f) {
  union { float f; unsigned u; } v; v.f = f;
  return (unsigned short)((v.u + 0x8000u) >> 16);
}
// pack two floats -> bf16 pair (low = f0) via v_perm_b32: 3 VALU ops
static __device__ __forceinline__ unsigned pack2(float f0, float f1) {
  union { float f; unsigned u; } a, b; a.f = f0; b.f = f1;
  return __builtin_amdgcn_perm(b.u + 0x8000u, a.u + 0x8000u, 0x07060302u);
}
static __device__ __forceinline__ float bf2f(unsigned short u) {
  union { unsigned u; float f; } v; v.u = ((unsigned)u) << 16;
  return v.f;
}
static __device__ __forceinline__ bf16x8 ldb(const unsigned short* p) {
  return *(const bf16x8*)p;
}
static __device__ __forceinline__ f32x4 mm(bf16x8 a, bf16x8 b, f32x4 c) {
  return __builtin_amdgcn_mfma_f32_16x16x32_bf16(a, b, c, 0, 0, 0);
}

// ------ Kernel 1: LN -> xn [b][n][c] bf16  (+ fused fp32->bf16 weight cvt) --
__global__ __launch_bounds__(256) void k_lncvt(const float* __restrict__ x,
                                               const float* __restrict__ gamma,
                                               unsigned short* __restrict__ xn,
                                               const float* __restrict__ wq,
                                               const float* __restrict__ wo,
                                               unsigned short* __restrict__ wqb,
                                               unsigned short* __restrict__ wob) {
  int blk = blockIdx.x;
  if (blk >= 256) {                       // weight convert: 256 blocks
    int t = (blk - 256) * 256 + threadIdx.x;
    int e = t * 4;
    if (e < 768 * 256) {
      float4 v = *(const float4*)(wq + e);
      u16x4 pk = { f2bfr(v.x), f2bfr(v.y), f2bfr(v.z), f2bfr(v.w) };
      *(u16x4*)(wqb + e) = pk;
    } else {
      int e2 = e - 768 * 256;
      float4 v = *(const float4*)(wo + e2);
      u16x4 pk = { f2bfr(v.x), f2bfr(v.y), f2bfr(v.z), f2bfr(v.w) };
      *(u16x4*)(wob + e2) = pk;
    }
    return;
  }
  int b  = blk >> 7;
  int n0 = (blk & 127) * 32;
  int t  = threadIdx.x;
  int nl = t & 31;
  int cg = t >> 5;                 // channel group 0..7 (32 channels each)
  int n  = n0 + nl;
  const float* xp = x + ((size_t)(b * CCH + cg * 32)) * NSEQ + n;
  float vals[32];
  float s = 0.f, s2 = 0.f;
#pragma unroll
  for (int j = 0; j < 32; j++) {
    float v = xp[(size_t)j * NSEQ];
    vals[j] = v; s += v; s2 += v * v;
  }
  __shared__ float rs[8][32], rs2[8][32];
  rs[cg][nl] = s; rs2[cg][nl] = s2;
  __syncthreads();
  float S = 0.f, S2 = 0.f;
#pragma unroll
  for (int g = 0; g < 8; g++) { S += rs[g][nl]; S2 += rs2[g][nl]; }
  float mean = S * (1.f / 256.f);
  float var  = S2 * (1.f / 256.f) - mean * mean;
  float rstd = rsqrtf(var + 1e-5f);
  unsigned short* dst = xn + ((size_t)b * NSEQ + n) * CCH + cg * 32;
#pragma unroll
  for (int j0 = 0; j0 < 32; j0 += 8) {
    u16x8 pk;
#pragma unroll
    for (int j = 0; j < 8; j++)
      pk[j] = f2bfr((vals[j0 + j] - mean) * rstd * gamma[cg * 32 + j0 + j]);
    *(u16x8*)(dst + j0) = pk;
  }
}

// --- Kernel 2: QKV GEMM + fused l2norm, BK=128 (3 barriers total) ----------
// Tiles staged via global_load_lds into stride-128 rows, XOR chunk swizzle.
// oi 0..3: q head oi -> qt (scaled 8*log2e); 4..7: k -> ktb; 8..11: v -> qkv.
__global__ __launch_bounds__(256) void k_qkv(const unsigned short* __restrict__ wqb,
                                             const unsigned short* __restrict__ xn,
                                             unsigned short* __restrict__ qkv,
                                             unsigned short* __restrict__ qt,
                                             unsigned short* __restrict__ ktb) {
  int n0 = blockIdx.x * 64;
  int oi = blockIdx.y;
  int o0 = oi * 64;
  int b  = blockIdx.z;
  __shared__ unsigned short Al[64 * 128];   // [o][k-local] swizzled, 16 KB
  __shared__ unsigned short Bl[64 * 128];   // [n][k-local] swizzled, 16 KB
  int t = threadIdx.x;
  int lane = t & 63, w = t >> 6;
  int c = lane & 15, quad = lane >> 4;
  int wm = w >> 1, wn = w & 1;
  f32x4 acc[2][2] = {};
  int lr = lane >> 4;                       // row within 4-row group
  int lchk = lane & 15;                     // phys chunk (16 chunks/row)
  const unsigned short* apg = wqb + (size_t)o0 * CCH;
  const unsigned short* bpg = xn + ((size_t)b * NSEQ + n0) * CCH;
  for (int kt = 0; kt < 2; kt++) {
    if (kt) __syncthreads();
#pragma unroll
    for (int q = 0; q < 4; q++) {
      int r = w * 16 + q * 4 + lr;
      int srcoff = r * CCH + kt * 128 + ((lchk ^ (r & 7)) * 8);
      GLD16(apg + srcoff, Al + (size_t)(w * 16 + q * 4) * 128);
      GLD16(bpg + srcoff, Bl + (size_t)(w * 16 + q * 4) * 128);
    }
    __syncthreads();
#pragma unroll
    for (int ks = 0; ks < 4; ks++) {
      int ra0 = wm * 32 + c, ra1 = ra0 + 16;
      int rb0 = wn * 32 + c, rb1 = rb0 + 16;
      bf16x8 a0 = ldb(&Al[ra0 * 128 + (((ks * 4 + quad) ^ (ra0 & 7)) * 8)]);
      bf16x8 a1 = ldb(&Al[ra1 * 128 + (((ks * 4 + quad) ^ (ra1 & 7)) * 8)]);
      bf16x8 b0 = ldb(&Bl[rb0 * 128 + (((ks * 4 + quad) ^ (rb0 & 7)) * 8)]);
      bf16x8 b1 = ldb(&Bl[rb1 * 128 + (((ks * 4 + quad) ^ (rb1 & 7)) * 8)]);
      acc[0][0] = mm(a0, b0, acc[0][0]);
      acc[0][1] = mm(a0, b1, acc[0][1]);
      acc[1][0] = mm(a1, b0, acc[1][0]);
      acc[1][1] = mm(a1, b1, acc[1][1]);
    }
  }
  if (oi < 8) {
    // per-n sum of squares: this wave covers d in [wm*32, wm*32+32)
    float* sq = (float*)Al;                 // reuse Al after final reads
    float s0 = 0.f, s1 = 0.f;
#pragma unroll
    for (int i = 0; i < 2; i++)
#pragma unroll
      for (int rr = 0; rr < 4; rr++) {
        s0 += acc[i][0][rr] * acc[i][0][rr];
        s1 += acc[i][1][rr] * acc[i][1][rr];
      }
    s0 += __shfl_xor(s0, 16); s0 += __shfl_xor(s0, 32);
    s1 += __shfl_xor(s1, 16); s1 += __shfl_xor(s1, 32);
    __syncthreads();
    if (quad == 0) {
      sq[wm * 64 + wn * 32 + c]      = s0;
      sq[wm * 64 + wn * 32 + 16 + c] = s1;
    }
    __syncthreads();
    float r0 = rsqrtf(sq[wn * 32 + c]      + sq[64 + wn * 32 + c]      + 1e-12f);
    float r1 = rsqrtf(sq[wn * 32 + 16 + c] + sq[64 + wn * 32 + 16 + c] + 1e-12f);
    if (oi < 4) { r0 *= 11.541560327111707f; r1 *= 11.541560327111707f; } // 8*log2e
    int h = oi & 3;
    unsigned short* base = (oi < 4 ? qt : ktb) + ((size_t)(b * NH + h) * NSEQ) * DH;
#pragma unroll
    for (int i = 0; i < 2; i++)
#pragma unroll
      for (int j = 0; j < 2; j++) {
        float rsc = j ? r1 : r0;
        int n = n0 + wn * 32 + j * 16 + c;
        int d = wm * 32 + i * 16 + quad * 4;
        uint2 pk = { pack2(acc[i][j][0] * rsc, acc[i][j][1] * rsc),
                     pack2(acc[i][j][2] * rsc, acc[i][j][3] * rsc) };
        *(uint2*)(base + (size_t)n * DH + d) = pk;
      }
  } else {
#pragma unroll
    for (int i = 0; i < 2; i++)
#pragma unroll
      for (int j = 0; j < 2; j++)
#pragma unroll
        for (int rr = 0; rr < 4; rr++) {
          int o = o0 + wm * 32 + i * 16 + quad * 4 + rr;
          int n = n0 + wn * 32 + j * 16 + c;
          qkv[((size_t)b * 768 + o) * NSEQ + n] = f2bfr(acc[i][j][rr]);
        }
  }
}

// ------ Kernel 3: flash attention, Q-tile 128, double-buffered K/V ----------
// Max-free softmax (|sim|<=8 folded as 8*log2e into q), split-KV. Single
// barrier per KV-tile: prefetch GLD16 into alternate buffers right after the
// barrier; the next barrier's vmcnt(0) drain lands after a full compute phase.
__global__ __launch_bounds__(256, 3) void k_attn(
    const unsigned short* __restrict__ qt,
    const unsigned short* __restrict__ ktb,
    const unsigned short* __restrict__ qkv,
    unsigned short* __restrict__ opart,
    float* __restrict__ lpart,
    int S, int kvlen) {
  int i0 = blockIdx.x * 128;
  int h  = blockIdx.y;
  int bz = blockIdx.z;
  int b  = bz / S, s = bz % S;
  __shared__ unsigned short Kl[2][64 * 64];  // [j][d] swizzled, 2x8 KB
  __shared__ unsigned short Vl[2][64 * 64];  // [d][j] swizzled, 2x8 KB
  __shared__ unsigned short Pl[128 * 64];    // per-wave P [i][j] swizzled, 16 KB
  int t = threadIdx.x;
  int lane = t & 63, w = t >> 6;
  int c = lane & 15, quad = lane >> 4;

  const unsigned short* qbase = qt  + ((size_t)(b * NH + h) * NSEQ) * DH;
  const unsigned short* kbase = ktb + ((size_t)(b * NH + h) * NSEQ) * DH;
  const unsigned short* vbase = qkv + ((size_t)b * 768 + 512 + h * 64) * NSEQ;

  // Q fragments straight from global (one-time, L2-served)
  int rlo = w * 32 + c, rhi = rlo + 16;     // local q-rows of this lane
  const unsigned short* qlo = qbase + (size_t)(i0 + rlo) * DH + quad * 8;
  const unsigned short* qhi = qlo + 16 * DH;
  bf16x8 qlo0 = ldb(qlo), qlo1 = ldb(qlo + 32);
  bf16x8 qhi0 = ldb(qhi), qhi1 = ldb(qhi + 32);

  u16x8 onesu;
#pragma unroll
  for (int j = 0; j < 8; j++) onesu[j] = 0x3F80;               // bf16 1.0
  bf16x8 ones = *(bf16x8*)&onesu;

  f32x4 acclo[4] = {}, acchi[4] = {};
  f32x4 accllo = {}, acclhi = {};

  // K/V staging: lane covers row w*16 + {0,8} + (lane>>3), phys chunk lane&7
  int slr = lane >> 3, slc = lane & 7;
  int ssw = (slc ^ slr) * 8;                // swizzled source elem offset
  const unsigned short* kp = kbase + (size_t)(s * kvlen + w * 16 + slr) * DH + ssw;
  const unsigned short* vp = vbase + (size_t)(w * 16 + slr) * NSEQ + s * kvlen + ssw;
  int sw0 = (quad ^ (c & 7)) * 8;           // ds_read swizzled chunk offsets
  int sw1 = sw0 ^ 32;
  int r7 = rlo & 7;                         // == rhi & 7

  int nIt = kvlen / 64;
  // prologue: prefetch tile 0 into buffer 0
  GLD16(kp,            &Kl[0][(w * 16)     * 64]);
  GLD16(kp + 8 * DH,   &Kl[0][(w * 16 + 8) * 64]);
  GLD16(vp,            &Vl[0][(w * 16)     * 64]);
  GLD16(vp + 8 * NSEQ, &Vl[0][(w * 16 + 8) * 64]);
  kp += 64 * DH; vp += 64;

  for (int it = 0; it < nIt; it++) {
    int cur = it & 1;
    __syncthreads();   // drains vmcnt(0): buf[cur] ready; prior reads done
    if (it + 1 < nIt) {
      int nb = cur ^ 1;
      GLD16(kp,            &Kl[nb][(w * 16)     * 64]);
      GLD16(kp + 8 * DH,   &Kl[nb][(w * 16 + 8) * 64]);
      GLD16(vp,            &Vl[nb][(w * 16)     * 64]);
      GLD16(vp + 8 * NSEQ, &Vl[nb][(w * 16 + 8) * 64]);
      kp += 64 * DH; vp += 64;
    }

    // S^T tiles for both q-sets; exp2 + pack + P-write consumed per jt
#pragma unroll
    for (int jt = 0; jt < 4; jt++) {
      bf16x8 k0 = ldb(&Kl[cur][(jt * 16 + c) * 64 + sw0]);
      bf16x8 k1 = ldb(&Kl[cur][(jt * 16 + c) * 64 + sw1]);
      f32x4 zl = {}; zl = mm(k0, qlo0, zl); zl = mm(k1, qlo1, zl);
      f32x4 zh = {}; zh = mm(k0, qhi0, zh); zh = mm(k1, qhi1, zh);
      int cj = jt * 2 + (quad >> 1);        // logical 8-elem chunk
      int sub = (quad & 1) * 4;
      uint2 pkl = { pack2(exp2f(zl[0]), exp2f(zl[1])),
                    pack2(exp2f(zl[2]), exp2f(zl[3])) };
      *(uint2*)&Pl[rlo * 64 + ((cj ^ r7) * 8) + sub] = pkl;
      uint2 pkh = { pack2(exp2f(zh[0]), exp2f(zh[1])),
                    pack2(exp2f(zh[2]), exp2f(zh[3])) };
      *(uint2*)&Pl[rhi * 64 + ((cj ^ r7) * 8) + sub] = pkh;
    }
    // P reads (same-wave rows; lgkmcnt orders write->read)
    bf16x8 plo0 = ldb(&Pl[rlo * 64 + ((quad ^ r7) * 8)]);
    bf16x8 plo1 = ldb(&Pl[rlo * 64 + (((quad + 4) ^ r7) * 8)]);
    bf16x8 phi0 = ldb(&Pl[rhi * 64 + ((quad ^ r7) * 8)]);
    bf16x8 phi1 = ldb(&Pl[rhi * 64 + (((quad + 4) ^ r7) * 8)]);
#pragma unroll
    for (int dt = 0; dt < 4; dt++) {
      bf16x8 v0 = ldb(&Vl[cur][(dt * 16 + c) * 64 + sw0]);
      bf16x8 v1 = ldb(&Vl[cur][(dt * 16 + c) * 64 + sw1]);
      acclo[dt] = mm(plo0, v0, acclo[dt]);
      acclo[dt] = mm(plo1, v1, acclo[dt]);
      acchi[dt] = mm(phi0, v0, acchi[dt]);
      acchi[dt] = mm(phi1, v1, acchi[dt]);
    }
    accllo = mm(plo0, ones, accllo); accllo = mm(plo1, ones, accllo);
    acclhi = mm(phi0, ones, acclhi); acclhi = mm(phi1, ones, acclhi);
  }

  size_t rb = ((size_t)(b * NH + h) * S + s) * NSEQ + i0 + w * 32;
  if (c == 0) {
#pragma unroll
    for (int rr = 0; rr < 4; rr++) {
      lpart[rb + quad * 4 + rr]      = accllo[rr];
      lpart[rb + 16 + quad * 4 + rr] = acclhi[rr];
    }
  }
#pragma unroll
  for (int rr = 0; rr < 4; rr++)
#pragma unroll
    for (int dt = 0; dt < 4; dt++) {
      opart[(rb + quad * 4 + rr) * 64 + dt * 16 + c]      = f2bfr(acclo[dt][rr]);
      opart[(rb + 16 + quad * 4 + rr) * 64 + dt * 16 + c] = f2bfr(acchi[dt][rr]);
    }
}

// ------ Kernel 3b: merge split-KV partials (plain sums) -> ao bf16 ----------
__global__ __launch_bounds__(256) void k_merge(
    const unsigned short* __restrict__ opart,
    const float* __restrict__ lpart,
    unsigned short* __restrict__ ao, int S) {
  int t = blockIdx.x * 256 + threadIdx.x;     // 131072 threads
  int row = t >> 2;                            // (b*NH+h)*NSEQ + i
  int dseg = (t & 3) * 16;
  int b = row >> 14, rem = row & 16383;
  int h = rem >> 12, i = rem & 4095;

  float l = 0.f;
  float o[16];
#pragma unroll
  for (int j = 0; j < 16; j++) o[j] = 0.f;
  for (int s = 0; s < S; s++) {
    size_t rb = ((size_t)(b * NH + h) * S + s) * NSEQ + i;
    l += lpart[rb];
    const unsigned short* p = opart + rb * 64 + dseg;
    u16x8 v0 = *(const u16x8*)p;
    u16x8 v1 = *(const u16x8*)(p + 8);
#pragma unroll
    for (int j = 0; j < 8; j++) {
      o[j]     += bf2f(v0[j]);
      o[8 + j] += bf2f(v1[j]);
    }
  }
  float inv = 1.f / l;
  unsigned short* dst = ao + ((size_t)b * NSEQ + i) * INNER + h * 64 + dseg;
  uint4 pk0 = { pack2(o[0] * inv, o[1] * inv),  pack2(o[2] * inv, o[3] * inv),
                pack2(o[4] * inv, o[5] * inv),  pack2(o[6] * inv, o[7] * inv) };
  uint4 pk1 = { pack2(o[8] * inv, o[9] * inv),  pack2(o[10] * inv, o[11] * inv),
                pack2(o[12] * inv, o[13] * inv),pack2(o[14] * inv, o[15] * inv) };
  *(uint4*)dst = pk0;
  *(uint4*)(dst + 8) = pk1;
}

// ------ Kernel 4: out-proj + residual, BK=128 (3 barriers total) ------------
__global__ __launch_bounds__(256) void k_out(const unsigned short* __restrict__ wob,
                                             const unsigned short* __restrict__ ao,
                                             const float* __restrict__ x,
                                             float* __restrict__ out) {
  int n0 = blockIdx.x * 64;
  int o0 = blockIdx.y * 64;
  int b  = blockIdx.z;
  __shared__ unsigned short Al[64 * 128];
  __shared__ unsigned short Bl[64 * 128];
  int t = threadIdx.x;
  int lane = t & 63, w = t >> 6;
  int c = lane & 15, quad = lane >> 4;
  int wm = w >> 1, wn = w & 1;
  f32x4 acc[2][2] = {};
  int lr = lane >> 4;
  int lchk = lane & 15;
  const unsigned short* apg = wob + (size_t)o0 * INNER;
  const unsigned short* bpg = ao + ((size_t)b * NSEQ + n0) * INNER;
  for (int kt = 0; kt < 2; kt++) {
    if (kt) __syncthreads();
#pragma unroll
    for (int q = 0; q < 4; q++) {
      int r = w * 16 + q * 4 + lr;
      int srcoff = r * INNER + kt * 128 + ((lchk ^ (r & 7)) * 8);
      GLD16(apg + srcoff, Al + (size_t)(w * 16 + q * 4) * 128);
      GLD16(bpg + srcoff, Bl + (size_t)(w * 16 + q * 4) * 128);
    }
    __syncthreads();
#pragma unroll
    for (int ks = 0; ks < 4; ks++) {
      int ra0 = wm * 32 + c, ra1 = ra0 + 16;
      int rb0 = wn * 32 + c, rb1 = rb0 + 16;
      bf16x8 a0 = ldb(&Al[ra0 * 128 + (((ks * 4 + quad) ^ (ra0 & 7)) * 8)]);
      bf16x8 a1 = ldb(&Al[ra1 * 128 + (((ks * 4 + quad) ^ (ra1 & 7)) * 8)]);
      bf16x8 b0 = ldb(&Bl[rb0 * 128 + (((ks * 4 + quad) ^ (rb0 & 7)) * 8)]);
      bf16x8 b1 = ldb(&Bl[rb1 * 128 + (((ks * 4 + quad) ^ (rb1 & 7)) * 8)]);
      acc[0][0] = mm(a0, b0, acc[0][0]);
      acc[0][1] = mm(a0, b1, acc[0][1]);
      acc[1][0] = mm(a1, b0, acc[1][0]);
      acc[1][1] = mm(a1, b1, acc[1][1]);
    }
  }
#pragma unroll
  for (int i = 0; i < 2; i++)
#pragma unroll
    for (int j = 0; j < 2; j++)
#pragma unroll
      for (int rr = 0; rr < 4; rr++) {
        int o = o0 + wm * 32 + i * 16 + quad * 4 + rr;
        int n = n0 + wn * 32 + j * 16 + c;
        size_t idx = ((size_t)b * CCH + o) * NSEQ + n;
        out[idx] = acc[i][j][rr] + x[idx];
      }
}

extern "C" void kernel_launch(void* const* d_in, const int* in_sizes, int n_in,
                              void* d_out, int out_size, void* d_ws, size_t ws_size,
                              hipStream_t stream) {
  const float* x     = (const float*)d_in[0];
  const float* gamma = (const float*)d_in[1];
  const float* wq    = (const float*)d_in[2];
  const float* wo    = (const float*)d_in[3];
  float* out = (float*)d_out;

  const size_t MB = 1u << 20;
  char* ws = (char*)d_ws;
  // ws layout:
  unsigned short* ao  = (unsigned short*)ws;                   // [0,4)  bf16 [B][N][256]
  unsigned short* xn  = (unsigned short*)(ws + 4 * MB);        // [4,8)  bf16 [B][N][256]
  unsigned short* qkv = (unsigned short*)(ws + 8 * MB);        // [8,20) bf16 [B][768][N] (v region used)
  unsigned short* wqb = (unsigned short*)(ws + 20 * MB);       // 384 KB
  unsigned short* wob = (unsigned short*)(ws + 20 * MB + 512 * 1024); // 128 KB
  unsigned short* qt  = (unsigned short*)(ws + 21 * MB);       // [21,25) bf16 [B][H][N][D]
  unsigned short* ktb = (unsigned short*)(ws + 25 * MB);       // [25,29) bf16 [B][H][N][D]
  unsigned short* opart = (unsigned short*)(ws + 29 * MB);     // S*B*H*N*64 bf16
  int S;
  if (ws_size >= 48 * MB) S = 4;
  else if (ws_size >= 40 * MB) S = 2;
  else S = 1;
  size_t opart_bytes = (size_t)S * BATCH * NH * NSEQ * DH * 2;
  float* lpart = (float*)(ws + 29 * MB + opart_bytes);
  int kvlen = NSEQ / S;

  k_lncvt<<<dim3(512),          256, 0, stream>>>(x, gamma, xn, wq, wo, wqb, wob);
  k_qkv  <<<dim3(64, 12, 2),    256, 0, stream>>>(wqb, xn, qkv, qt, ktb);
  k_attn <<<dim3(32, 4, 2 * S), 256, 0, stream>>>(qt, ktb, qkv, opart,
                                                  lpart, S, kvlen);
  k_merge<<<dim3(512),          256, 0, stream>>>(opart, lpart, ao, S);
  k_out  <<<dim3(64, 4, 2),     256, 0, stream>>>(wob, ao, x, out);
}